// Round 14
// baseline (943.238 us; speedup 1.0000x reference)
//
#include <hip/hip_runtime.h>
#include <hip/hip_bf16.h>

// ---------------------------------------------------------------------------
// THEGCNModel — R14 (on R13):
//   * Occupancy raise where register footprint << cap (R13 evidence:
//     phase1 VGPR=64, LDS 28.2KB, occupancy 32% = grid-limited at 3 blk/CU):
//     phase1 bounds(256,5) grid 1280 (5 blk/CU); phase2 bounds(256,6) grid
//     1536 (6 blk/CU). Unlike R6/R7, footprint (64/52) is far below caps
//     (102/85) so no remat risk.
//   * acc2 memset (25.6MB) folded into phase1_node's store loop.
// ---------------------------------------------------------------------------

typedef float  f32x4 __attribute__((ext_vector_type(4)));
typedef short  s16x8 __attribute__((ext_vector_type(8)));

__device__ __forceinline__ float tanh_factor(float u) {
  // 2*tanh(u)-1 == 1 - 4/(exp(2u)+1); rcp is 1-ulp approx (noise vs bf16)
  float e = __expf(2.0f * u);
  return fmaf(-4.0f, __builtin_amdgcn_rcpf(e + 1.0f), 1.0f);
}

__device__ __forceinline__ void atomic_add_f32(float* p, float v) {
  unsafeAtomicAdd(p, v);               // native global_atomic_add_f32
}

__device__ __forceinline__ unsigned short f2bf(float f) {
  __hip_bfloat16 b = __float2bfloat16(f);
  return *(unsigned short*)&b;
}
__device__ __forceinline__ float bf2f(unsigned short u) {
  unsigned int v = ((unsigned int)u) << 16;
  return *(float*)&v;
}

// ---------------------------------------------------------------------------
// Counting sort by dst: histogram -> scan -> expand(dstS) -> scatter(src,dts).
// ---------------------------------------------------------------------------
__global__ __launch_bounds__(256) void k_hist(
    const int* __restrict__ ei, int* __restrict__ cntI, int E)
{
  int e = blockIdx.x * 256 + threadIdx.x;
  if (e < E) atomicAdd(&cntI[__builtin_nontemporal_load(ei + E + e)], 1);
}

__global__ __launch_bounds__(256) void k_scan_block(
    const int* __restrict__ cntI, int* __restrict__ cursor,
    int* __restrict__ bsum, int N)
{
  __shared__ int s[256];
  const int t = threadIdx.x;
  int i = blockIdx.x * 256 + t;
  int v = (i < N) ? cntI[i] : 0;
  s[t] = v;
  for (int off = 1; off < 256; off <<= 1) {
    __syncthreads();
    int x = (t >= off) ? s[t - off] : 0;
    __syncthreads();
    s[t] += x;
  }
  __syncthreads();
  if (i < N) cursor[i] = s[t] - v;          // local exclusive
  if (t == 255) bsum[blockIdx.x] = s[255];
}

__global__ __launch_bounds__(512) void k_scan_bsum(int* __restrict__ bsum, int nb)
{
  __shared__ int s[512];
  const int t = threadIdx.x;
  int v = (t < nb) ? bsum[t] : 0;
  s[t] = v;
  for (int off = 1; off < 512; off <<= 1) {
    __syncthreads();
    int x = (t >= off) ? s[t - off] : 0;
    __syncthreads();
    s[t] += x;
  }
  __syncthreads();
  if (t < nb) bsum[t] = s[t] - v;           // exclusive
}

// fused: cursor += block offset (final rowPtr) AND expand dstS runs.
__global__ __launch_bounds__(256) void k_expand_add(
    int* __restrict__ cursor, const int* __restrict__ bsum,
    const int* __restrict__ cntI, int* __restrict__ dstS, int N)
{
  int n = blockIdx.x * 256 + threadIdx.x;
  if (n >= N) return;
  int cur = cursor[n] + bsum[blockIdx.x];
  cursor[n] = cur;
  int c = cntI[n];
  for (int i = 0; i < c; i++) dstS[cur + i] = n;
}

// XCD-partitioned scatter: group g = blockIdx&7 handles dst in [N*g/8,N*(g+1)/8)
// -> its srcdtS segment (~1.6MB) fits one XCD L2, lines fill fully.
__global__ __launch_bounds__(256) void k_scatter_x(
    const int* __restrict__ ei, const float* __restrict__ dts,
    int* __restrict__ cursor, int2* __restrict__ srcdtS, int E, int N)
{
  const int g  = blockIdx.x & 7;           // XCD proxy (round-robin heuristic)
  const int bi = blockIdx.x >> 3;
  const int nb = gridDim.x >> 3;
  const int lo = (int)(((long long)N * g) >> 3);
  const int hi = (int)(((long long)N * (g + 1)) >> 3);
  for (int e = bi * 256 + threadIdx.x; e < E; e += nb * 256) {
    int d = __builtin_nontemporal_load(ei + E + e);
    if (d >= lo && d < hi) {
      int s = __builtin_nontemporal_load(ei + e);
      float dt = __builtin_nontemporal_load(dts + e);
      int pos = atomicAdd(&cursor[d], 1);
      srcdtS[pos] = make_int2(s, __float_as_int(dt));
    }
  }
}

// ---------------------------------------------------------------------------
// prep_all: xb = bf16(x) padded to 24 cols; phase-1 weights W1t1/W2t1; phase-2
// weights W1t/W2t; classifier weights cW1t[c:64][k:64], cW2t[c:32][k:64].
// ---------------------------------------------------------------------------
__global__ __launch_bounds__(256) void prep_all(
    const float* __restrict__ x, const float* __restrict__ tW1,
    const float* __restrict__ tW2, const float* __restrict__ sW1,
    const float* __restrict__ sW2, const float* __restrict__ cW1,
    const float* __restrict__ cW2, unsigned short* __restrict__ xb,
    unsigned short* __restrict__ W1t1, unsigned short* __restrict__ W2t1,
    unsigned short* __restrict__ W1t, unsigned short* __restrict__ W2t,
    unsigned short* __restrict__ cW1t, unsigned short* __restrict__ cW2t, int N)
{
  int i = blockIdx.x * 256 + threadIdx.x;
  int totalX = N * 24;
  for (int idx = i; idx < totalX; idx += gridDim.x * 256) {
    int n = idx / 24, c = idx - n * 24;
    xb[idx] = (c < 17) ? f2bf(x[n * 17 + c]) : (unsigned short)0;
  }
  if (i < 48 * 96) {
    int n = i / 96, k = i - n * 96;
    int src = (k < 17) ? k : (k >= 24 && k < 41) ? (k - 24 + 17)
            : (k >= 48 && k < 80) ? (k - 48 + 34) : -1;
    W1t1[i] = (n < 33 && src >= 0) ? f2bf(tW1[src * 33 + n]) : (unsigned short)0;
  }
  if (i < 32 * 64) {
    int n = i / 64, k = i - n * 64;
    W2t1[i] = (n < 17 && k < 33) ? f2bf(tW2[k * 17 + n]) : (unsigned short)0;
  }
  if (i < 2 * 64 * 128) {
    int l = i >> 13; int r = i & 8191; int n = r >> 7; int k = r & 127;
    W1t[i] = f2bf(sW1[((size_t)l * 128 + k) * 64 + n]);
  }
  if (i < 2 * 64 * 64) {
    int l = i >> 12; int r = i & 4095; int n = r >> 6; int k = r & 63;
    W2t[i] = f2bf(sW2[((size_t)l * 64 + k) * 64 + n]);
  }
  if (i < 64 * 64) {
    int c = i >> 6, k = i & 63;
    cW1t[i] = f2bf(cW1[k * 64 + c]);
  }
  if (i < 32 * 64) {
    int c = i >> 6, k = i & 63;
    cW2t[i] = f2bf(cW2[k * 32 + c]);
  }
}

// ---------------------------------------------------------------------------
// Phase 1 edge kernel (MFMA, barrier-free wave-private 16-edge tiles).
// ---------------------------------------------------------------------------
__global__ __launch_bounds__(256, 5) void phase1_edge_mfma(
    const unsigned short* __restrict__ xb, const int* __restrict__ dstS,
    const int2* __restrict__ srcdtS, const float* __restrict__ freq,
    const float* __restrict__ phs,
    const unsigned short* __restrict__ W1t1, const float* __restrict__ b1,
    const unsigned short* __restrict__ W2t1, const float* __restrict__ b2,
    float* __restrict__ accum, int E, int nwt)
{
  __shared__ unsigned short sA[64][104];
  __shared__ unsigned short sHid[64][72];
  __shared__ float sRed[64][20];
  __shared__ int   sDst[64];

  const int t = threadIdx.x;
  const int wv = t >> 6, lane = t & 63, l16 = lane & 15, quad = lane >> 4;
  const int r0 = wv * 16;

  s16x8 w1f[3][3], w2f[2][2];
  float bias1[3], bias2[2];
#pragma unroll
  for (int cb = 0; cb < 3; cb++) {
    int n = cb * 16 + l16;
#pragma unroll
    for (int kb = 0; kb < 3; kb++)
      w1f[cb][kb] = *(const s16x8*)&W1t1[n * 96 + kb * 32 + quad * 8];
    bias1[cb] = (n < 33) ? b1[n] : 0.0f;
  }
#pragma unroll
  for (int cb = 0; cb < 2; cb++) {
    int n = cb * 16 + l16;
#pragma unroll
    for (int kb = 0; kb < 2; kb++)
      w2f[cb][kb] = *(const s16x8*)&W2t1[n * 64 + kb * 32 + quad * 8];
    bias2[cb] = (n < 17) ? b2[n] : 0.0f;
  }

  // zero own-wave pad columns once
  for (int i = lane; i < 16 * 28; i += 64) {
    int rr = r0 + i / 28, c = i % 28;
    int col = (c < 6) ? 18 + c : (c < 12) ? 42 + (c - 6) : 80 + (c - 12);
    sA[rr][col] = 0;
  }
  for (int i = lane; i < 256; i += 64)
    sHid[r0 + (i >> 4)][48 + (i & 15)] = 0;

  const int gw = blockIdx.x * 4 + wv;
  const int nw = gridDim.x * 4;

  for (int tile = gw; tile < nwt; tile += nw) {
    const int eb = tile << 4;

    // staging: 4 lanes/edge (q0 xi, q1 xj, q2/q3 rel halves) — own rows only
    {
      int e_loc = lane >> 2, q = lane & 3;
      int rr = r0 + e_loc;
      int er = eb + e_loc; if (er >= E) er = E - 1;
      if (q < 2) {
        int node = q ? srcdtS[er].x : dstS[er];
        if (!q) sDst[rr] = node;
        const unsigned short* src = &xb[(size_t)node * 24];
        int base = q ? 24 : 0;
        *(uint4*)&sA[rr][base]     = *(const uint4*)&src[0];
        *(uint4*)&sA[rr][base + 8] = *(const uint4*)&src[8];
        *(unsigned int*)&sA[rr][base + 16] = *(const unsigned int*)&src[16];
      } else {
        float dt = __int_as_float(srcdtS[er].y);
        int k0 = (q == 2) ? 0 : 16;
        unsigned short tmp[16] __attribute__((aligned(16)));
#pragma unroll
        for (int j = 0; j < 16; j++)
          tmp[j] = f2bf(__cosf(fmaf(dt, freq[k0 + j], phs[k0 + j])));
        *(uint4*)&sA[rr][48 + k0]     = *(const uint4*)&tmp[0];
        *(uint4*)&sA[rr][48 + k0 + 8] = *(const uint4*)&tmp[8];
      }
    }

    // pass1: hid = relu(A @ W1 + b1)   (own row r0+l16)
    f32x4 a1[3];
#pragma unroll
    for (int cb = 0; cb < 3; cb++)
      a1[cb] = (f32x4){bias1[cb], bias1[cb], bias1[cb], bias1[cb]};
#pragma unroll
    for (int kb = 0; kb < 3; kb++) {
      s16x8 aF = *(const s16x8*)&sA[r0 + l16][kb * 32 + quad * 8];
#pragma unroll
      for (int cb = 0; cb < 3; cb++)
        a1[cb] = __builtin_amdgcn_mfma_f32_16x16x32_bf16(aF, w1f[cb][kb], a1[cb], 0, 0, 0);
    }
#pragma unroll
    for (int cb = 0; cb < 3; cb++)
#pragma unroll
      for (int reg = 0; reg < 4; reg++)
        sHid[r0 + quad * 4 + reg][cb * 16 + l16] = f2bf(fmaxf(a1[cb][reg], 0.0f));

    // pass2: u = hid @ W2 + b2
    f32x4 a2[2];
#pragma unroll
    for (int cb = 0; cb < 2; cb++)
      a2[cb] = (f32x4){bias2[cb], bias2[cb], bias2[cb], bias2[cb]};
#pragma unroll
    for (int kb = 0; kb < 2; kb++) {
      s16x8 aF = *(const s16x8*)&sHid[r0 + l16][kb * 32 + quad * 8];
#pragma unroll
      for (int cb = 0; cb < 2; cb++)
        a2[cb] = __builtin_amdgcn_mfma_f32_16x16x32_bf16(aF, w2f[cb][kb], a2[cb], 0, 0, 0);
    }

    // f -> sRed (own rows)
#pragma unroll
    for (int reg = 0; reg < 4; reg++) {
      int row = r0 + quad * 4 + reg;
      bool ok = (eb + quad * 4 + reg < E);
      sRed[row][l16] = ok ? tanh_factor(a2[0][reg]) : 0.0f;
      if (l16 == 0) sRed[row][16] = ok ? tanh_factor(a2[1][reg]) : 0.0f;
    }

    // wave-local segmented walk: lanes 0..16, col = lane, own 16 rows
    if (lane < 17) {
      int col = lane;
      float run = 0.0f;
      int cur = sDst[r0];
#pragma unroll
      for (int k = 0; k < 16; k++) {
        int d = sDst[r0 + k];
        float v = sRed[r0 + k][col];
        if (d != cur) {
          atomic_add_f32(&accum[(size_t)cur * 17 + col], run);
          run = 0.0f; cur = d;
        }
        run += v;
      }
      atomic_add_f32(&accum[(size_t)cur * 17 + col], run);
    }
  }
}

// ---------------------------------------------------------------------------
// Phase 1 node kernel: h[n] = (x[n] * (1 + acc/max(cnt,1))) @ projW + projb.
// Also zeroes acc2 (replaces a 25.6MB memset dispatch).
// ---------------------------------------------------------------------------
__global__ __launch_bounds__(256) void phase1_node(
    const float* __restrict__ x, const float* __restrict__ acc1,
    const int* __restrict__ cntI, const float* __restrict__ Wp,
    const float* __restrict__ bp, float* __restrict__ h,
    float* __restrict__ acc2, int N)
{
  __shared__ float s0[4][20];
  const int t = threadIdx.x;
  const int nb = blockIdx.x << 2;
  if (t < 68) {
    int nl = t / 17, c = t % 17;
    int n = nb + nl;
    float v = 0.0f;
    if (n < N) {
      float cnt = fmaxf((float)cntI[n], 1.0f);
      v = x[n * 17 + c] * (1.0f + acc1[n * 17 + c] / cnt);
    }
    s0[nl][c] = v;
  }
  __syncthreads();
  int nl = t >> 6, j = t & 63;
  int n = nb + nl;
  if (n < N) {
    float acc = bp[j];
#pragma unroll
    for (int c = 0; c < 17; c++) acc = fmaf(s0[nl][c], Wp[c * 64 + j], acc);
    h[n * 64 + j] = acc;
    acc2[n * 64 + j] = 0.0f;
  }
}

// ---------------------------------------------------------------------------
// prep_P: P1[n] = h[n]@W1a + b1, P2[n] = h[n]@W1b (dense per-node, MFMA).
// ---------------------------------------------------------------------------
__global__ void prep_P(
    const float* __restrict__ h, const unsigned short* __restrict__ W1t,
    const float* __restrict__ b1, unsigned short* __restrict__ P1,
    unsigned short* __restrict__ P2, int N)
{
  __shared__ unsigned short sH[64][72];
  const int t = threadIdx.x;
  const int wv = t >> 6, lane = t & 63, l16 = lane & 15, quad = lane >> 4;
  const int nb = blockIdx.x << 6;

#pragma unroll
  for (int i = 0; i < 4; i++) {
    int g = t + i * 256;
    int r = g >> 4, c4 = (g & 15) << 2;
    int n = nb + r; if (n >= N) n = N - 1;
    float4 v = *(const float4*)&h[(size_t)n * 64 + c4];
    ushort4 o = { f2bf(v.x), f2bf(v.y), f2bf(v.z), f2bf(v.w) };
    *(ushort4*)&sH[r][c4] = o;
  }
  __syncthreads();

  const int n = nb + wv * 16 + l16;
#pragma unroll
  for (int half = 0; half < 2; half++) {
    f32x4 acc[4];
#pragma unroll
    for (int cb = 0; cb < 4; cb++) {
      if (half == 0) {
        float4 bv = *(const float4*)&b1[cb * 16 + quad * 4];
        acc[cb] = (f32x4){bv.x, bv.y, bv.z, bv.w};
      } else {
        acc[cb] = (f32x4){0.0f, 0.0f, 0.0f, 0.0f};
      }
    }
#pragma unroll
    for (int kb = 0; kb < 2; kb++) {
      s16x8 bF = *(const s16x8*)&sH[wv * 16 + l16][kb * 32 + quad * 8];
#pragma unroll
      for (int cb = 0; cb < 4; cb++) {
        s16x8 aF = *(const s16x8*)&W1t[(cb * 16 + l16) * 128 + half * 64 + kb * 32 + quad * 8];
        acc[cb] = __builtin_amdgcn_mfma_f32_16x16x32_bf16(aF, bF, acc[cb], 0, 0, 0);
      }
    }
    if (n < N) {
      unsigned short* P = half ? P2 : P1;
#pragma unroll
      for (int cb = 0; cb < 4; cb++) {
        ushort4 o = { f2bf(acc[cb][0]), f2bf(acc[cb][1]),
                      f2bf(acc[cb][2]), f2bf(acc[cb][3]) };
        *(ushort4*)&P[(size_t)n * 64 + cb * 16 + quad * 4] = o;
      }
    }
  }
}

// ---------------------------------------------------------------------------
// Phase 2 edge kernel — barrier-free wave-private 16-edge tiles.
// ---------------------------------------------------------------------------
__global__ __launch_bounds__(256, 6) void phase2_edge(
    const unsigned short* __restrict__ P1, const unsigned short* __restrict__ P2,
    const int* __restrict__ dstS, const int2* __restrict__ srcdtS,
    const unsigned short* __restrict__ W2t, const float* __restrict__ b2,
    float* __restrict__ accum, int E, int nwt)
{
  __shared__ unsigned short sA[64][136];   // [edge][0:64]=P1[dst], [64:128]=P2[src]
  __shared__ int sDst[64];
  float* sRedF = (float*)&sA[0][0];        // aliased 64x68 f32 (same stride 272B)

  const int t = threadIdx.x;
  const int wv = t >> 6, lane = t & 63, l16 = lane & 15, quad = lane >> 4;
  const int r0 = wv * 16;

  s16x8 w2f[4][2];
  f32x4 bias2v[4];
#pragma unroll
  for (int cb = 0; cb < 4; cb++) {
#pragma unroll
    for (int kb = 0; kb < 2; kb++)
      w2f[cb][kb] = *(const s16x8*)&W2t[(cb * 16 + l16) * 64 + kb * 32 + quad * 8];
    float4 bv = *(const float4*)&b2[cb * 16 + quad * 4];
    bias2v[cb] = (f32x4){bv.x, bv.y, bv.z, bv.w};
  }

  const int gw = blockIdx.x * 4 + wv;
  const int nw = gridDim.x * 4;
  const int eRow = r0 + l16;

  for (int tile = gw; tile < nwt; tile += nw) {
    const int eb = tile << 4;

    // staging: 4 lanes/edge, 64B contiguous per lane, own rows only
    {
      int e_loc = lane >> 2, q = lane & 3;
      int rr = r0 + e_loc;
      int er = eb + e_loc; if (er >= E) er = E - 1;
      int node;
      if (q < 2) { node = dstS[er]; if (!q) sDst[rr] = node; }
      else       node = srcdtS[er].x;
      const unsigned short* src = (q < 2 ? P1 : P2) + (size_t)node * 64 + (q & 1) * 32;
      int cb0 = q * 32;
#pragma unroll
      for (int j = 0; j < 4; j++)
        *(uint4*)&sA[rr][cb0 + j * 8] = *(const uint4*)&src[j * 8];
    }

    // hidden B-frags: relu(P1+P2), packed bf16 (own row)
    s16x8 hidf[2];
#pragma unroll
    for (int kb = 0; kb < 2; kb++) {
      s16x8 x1 = *(const s16x8*)&sA[eRow][kb * 32 + quad * 8];
      s16x8 x2 = *(const s16x8*)&sA[eRow][64 + kb * 32 + quad * 8];
      s16x8 hf;
#pragma unroll
      for (int j = 0; j < 8; j++) {
        float a = bf2f((unsigned short)x1[j]);
        float b = bf2f((unsigned short)x2[j]);
        hf[j] = (short)f2bf(fmaxf(a + b, 0.0f));
      }
      hidf[kb] = hf;
    }

    // u^T[n2][edge] = W2t @ hidden^T + b2
    f32x4 acc[4];
#pragma unroll
    for (int cb = 0; cb < 4; cb++) acc[cb] = bias2v[cb];
#pragma unroll
    for (int kb = 0; kb < 2; kb++)
#pragma unroll
      for (int cb = 0; cb < 4; cb++)
        acc[cb] = __builtin_amdgcn_mfma_f32_16x16x32_bf16(w2f[cb][kb], hidf[kb], acc[cb], 0, 0, 0);

    // f = 2*tanh(u)-1 -> sRedF (own rows; same-wave ordering)
    bool ok = (eb + l16 < E);
#pragma unroll
    for (int cb = 0; cb < 4; cb++) {
      f32x4 f;
#pragma unroll
      for (int reg = 0; reg < 4; reg++)
        f[reg] = ok ? tanh_factor(acc[cb][reg]) : 0.0f;
      *(f32x4*)&sRedF[eRow * 68 + cb * 16 + quad * 4] = f;
    }

    // wave-local segmented walk: lane = col, own 16 rows
    {
      float run = 0.0f;
      int cur = sDst[r0];
#pragma unroll
      for (int k = 0; k < 16; k++) {
        int d = sDst[r0 + k];                 // wave-uniform
        float v = sRedF[(r0 + k) * 68 + lane];
        if (d != cur) {                       // wave-uniform branch
          atomic_add_f32(&accum[(size_t)cur * 64 + lane], run);
          run = 0.0f; cur = d;
        }
        run += v;
      }
      atomic_add_f32(&accum[(size_t)cur * 64 + lane], run);
    }
  }
}

// ---------------------------------------------------------------------------
// Node update + BN statistics; re-zeroes accum for the next layer.
// ---------------------------------------------------------------------------
__global__ __launch_bounds__(256) void node_update_bn(
    float* __restrict__ h, float* __restrict__ accum,
    const int* __restrict__ cntI, float* __restrict__ bns,
    float* __restrict__ bnq, int N)
{
  const int t = threadIdx.x;
  float ls = 0.0f, lq = 0.0f;
  int total = N * 64;
  for (int idx = blockIdx.x * 256 + t; idx < total; idx += gridDim.x * 256) {
    int n = idx >> 6;
    float cnt = fmaxf((float)cntI[n], 1.0f);
    float v = h[idx] * (1.0f + accum[idx] / cnt);
    accum[idx] = 0.0f;                 // ready for next layer's scatter
    h[idx] = v;
    ls += v; lq += v * v;
  }
  __shared__ float ss[256], sq[256];
  ss[t] = ls; sq[t] = lq;
  __syncthreads();
  if (t < 64) {
    float s = ss[t] + ss[t + 64] + ss[t + 128] + ss[t + 192];
    float q = sq[t] + sq[t + 64] + sq[t + 128] + sq[t + 192];
    atomic_add_f32(&bns[t], s);
    atomic_add_f32(&bnq[t], q);
  }
}

// ---------------------------------------------------------------------------
// BN apply + relu (in place).
// ---------------------------------------------------------------------------
__global__ __launch_bounds__(256) void bn_apply_relu(
    float* __restrict__ d, const float* __restrict__ bns,
    const float* __restrict__ bnq, const float* __restrict__ gam,
    const float* __restrict__ bet, int total, int cmask, float invRows)
{
  for (int idx = blockIdx.x * 256 + threadIdx.x; idx < total;
       idx += gridDim.x * 256) {
    int c = idx & cmask;
    float m = bns[c] * invRows;
    float var = bnq[c] * invRows - m * m;
    float sc = gam[c] * rsqrtf(var + 1e-5f);
    d[idx] = fmaxf((d[idx] - m) * sc + bet[c], 0.0f);
  }
}

// ---------------------------------------------------------------------------
// Classifier MFMA (prep_P operand-swap pattern, K=64, COUT = NCB*16):
// z[n][c] f32 + fused BN stats (shfl-reduce over l16 rows, atomic per col).
// ---------------------------------------------------------------------------
template <int NCB>
__global__ __launch_bounds__(256) void clf_mfma(
    const float* __restrict__ in, const unsigned short* __restrict__ Wt,
    const float* __restrict__ bias, float* __restrict__ z,
    float* __restrict__ bns, float* __restrict__ bnq, int rows)
{
  __shared__ unsigned short sIn[64][72];
  const int t = threadIdx.x;
  const int wv = t >> 6, lane = t & 63, l16 = lane & 15, quad = lane >> 4;
  const int nb = blockIdx.x << 6;

  s16x8 wf[NCB][2];
  f32x4 bv[NCB];
#pragma unroll
  for (int cb = 0; cb < NCB; cb++) {
#pragma unroll
    for (int kb = 0; kb < 2; kb++)
      wf[cb][kb] = *(const s16x8*)&Wt[(cb * 16 + l16) * 64 + kb * 32 + quad * 8];
    float4 b4 = *(const float4*)&bias[cb * 16 + quad * 4];
    bv[cb] = (f32x4){b4.x, b4.y, b4.z, b4.w};
  }

#pragma unroll
  for (int i = 0; i < 4; i++) {
    int g = t + i * 256;
    int r = g >> 4, c4 = (g & 15) << 2;
    int n = nb + r; if (n >= rows) n = rows - 1;
    float4 v = *(const float4*)&in[(size_t)n * 64 + c4];
    ushort4 o = { f2bf(v.x), f2bf(v.y), f2bf(v.z), f2bf(v.w) };
    *(ushort4*)&sIn[r][c4] = o;
  }
  __syncthreads();

  const int n = nb + wv * 16 + l16;
  const bool ok = (n < rows);
  f32x4 acc[NCB];
#pragma unroll
  for (int cb = 0; cb < NCB; cb++) acc[cb] = bv[cb];
#pragma unroll
  for (int kb = 0; kb < 2; kb++) {
    s16x8 bF = *(const s16x8*)&sIn[wv * 16 + l16][kb * 32 + quad * 8];
#pragma unroll
    for (int cb = 0; cb < NCB; cb++)
      acc[cb] = __builtin_amdgcn_mfma_f32_16x16x32_bf16(wf[cb][kb], bF, acc[cb], 0, 0, 0);
  }

  // store z (f32) + per-col stats reduced over the wave's 16 rows
#pragma unroll
  for (int cb = 0; cb < NCB; cb++) {
    if (ok)
      *(float4*)&z[(size_t)n * (NCB * 16) + cb * 16 + quad * 4] =
          make_float4(acc[cb][0], acc[cb][1], acc[cb][2], acc[cb][3]);
    f32x4 s, q;
#pragma unroll
    for (int reg = 0; reg < 4; reg++) {
      float v = ok ? acc[cb][reg] : 0.0f;
      s[reg] = v; q[reg] = v * v;
    }
#pragma unroll
    for (int m = 1; m < 16; m <<= 1) {
#pragma unroll
      for (int reg = 0; reg < 4; reg++) {
        s[reg] += __shfl_xor(s[reg], m);
        q[reg] += __shfl_xor(q[reg], m);
      }
    }
    if (l16 == 0) {
#pragma unroll
      for (int reg = 0; reg < 4; reg++) {
        int col = cb * 16 + quad * 4 + reg;
        atomic_add_f32(&bns[col], s[reg]);
        atomic_add_f32(&bnq[col], q[reg]);
      }
    }
  }
}

__global__ __launch_bounds__(256) void clf_final(
    const float* __restrict__ z2, const float* __restrict__ W3,
    const float* __restrict__ b3, float* __restrict__ out, int rows)
{
  int n = blockIdx.x * 256 + threadIdx.x;
  if (n >= rows) return;
  float acc = b3[0];
#pragma unroll
  for (int k = 0; k < 32; k++) acc = fmaf(z2[n * 32 + k], W3[k], acc);
  out[n] = acc;
}

// ---------------------------------------------------------------------------
extern "C" void kernel_launch(void* const* d_in, const int* in_sizes, int n_in,
                              void* d_out, int out_size, void* d_ws, size_t ws_size,
                              hipStream_t stream)
{
  const float* x    = (const float*)d_in[0];
  const int*   ei   = (const int*)  d_in[1];
  const float* dts  = (const float*)d_in[2];
  const float* freq = (const float*)d_in[4];
  const float* phs  = (const float*)d_in[5];
  const float* tW1  = (const float*)d_in[6];
  const float* tb1  = (const float*)d_in[7];
  const float* tW2  = (const float*)d_in[8];
  const float* tb2  = (const float*)d_in[9];
  const float* pW   = (const float*)d_in[10];
  const float* pb   = (const float*)d_in[11];
  const float* sW1  = (const float*)d_in[12];
  const float* sb1  = (const float*)d_in[13];
  const float* sW2  = (const float*)d_in[14];
  const float* sb2  = (const float*)d_in[15];
  const float* bng  = (const float*)d_in[16];
  const float* bnb  = (const float*)d_in[17];
  const float* cW1  = (const float*)d_in[18];
  const float* cb1  = (const float*)d_in[19];
  const float* cg1  = (const float*)d_in[20];
  const float* cbb1 = (const float*)d_in[21];
  const float* cW2  = (const float*)d_in[22];
  const float* cb2  = (const float*)d_in[23];
  const float* cg2  = (const float*)d_in[24];
  const float* cbb2 = (const float*)d_in[25];
  const float* cW3  = (const float*)d_in[26];
  const float* cb3  = (const float*)d_in[27];
  float* out = (float*)d_out;

  const int N = in_sizes[0] / 17;
  const int E = in_sizes[1] / 2;
  const int B = out_size;

  // ---- workspace layout (byte offsets, union region for phase-local data) --
  char* base = (char*)d_ws;
  size_t off = 0;
  float* h    = (float*)(base + off); off += (size_t)N * 64 * 4;
  float* acc2 = (float*)(base + off); off += (size_t)N * 64 * 4;
  char*  uni  = base + off;           off += (size_t)N * 64 * 4;  // union
  float* bnsAll = (float*)(base + off); off += 8 * 64 * 4;        // 8 slots
  unsigned short* W1t = (unsigned short*)(base + off); off += 2 * 64 * 128 * 2;
  unsigned short* W2t = (unsigned short*)(base + off); off += 2 * 64 * 64 * 2;
  unsigned short* cW1t = (unsigned short*)(base + off); off += 64 * 64 * 2;
  unsigned short* cW2t = (unsigned short*)(base + off); off += 32 * 64 * 2;
  int* cntI   = (int*)(base + off); off += (size_t)N * 4;
  int* cursor = (int*)(base + off); off += (size_t)N * 4;
  int* bsum   = (int*)(base + off); off += 512 * 4;
  int* dstS   = (int*)(base + off); off += (size_t)E * 4;
  off = (off + 15) & ~(size_t)15;
  int2* srcdtS = (int2*)(base + off); off += (size_t)E * 8;
  size_t needed = off;
  if (ws_size < needed) return;  // fail visibly (output stays poisoned)

  // union members (phase1 | phase2 | classifier — lifetimes disjoint)
  float* acc1 = (float*)uni;                                     // N*17 f32
  unsigned short* xb   = (unsigned short*)(uni + (size_t)N * 17 * 4); // N*24
  unsigned short* W1t1 = xb + (size_t)N * 24;                    // 48*96
  unsigned short* W2t1 = W1t1 + 48 * 96;                         // 32*64
  unsigned short* P1 = (unsigned short*)uni;                     // N*64
  unsigned short* P2 = P1 + (size_t)N * 64;                      // N*64
  float* z1 = (float*)uni;                                       // B*64
  float* z2 = z1 + (size_t)B * 64;                               // B*32

  const int nwt = (E + 15) / 16;
  const int NB = (N + 255) / 256;
  if (NB > 512) return;

  // ---- init (poisoned ws): counts, acc1, BN-stat slots ----
  hipMemsetAsync(cntI, 0, (size_t)N * 4, stream);
  hipMemsetAsync(acc1, 0, (size_t)N * 17 * 4, stream);
  hipMemsetAsync(bnsAll, 0, 8 * 64 * 4, stream);

  // ---- counting sort by dst (yields counts + dstS) + weight/x prep ----
  k_hist<<<(E + 255) / 256, 256, 0, stream>>>(ei, cntI, E);
  k_scan_block<<<NB, 256, 0, stream>>>(cntI, cursor, bsum, N);
  k_scan_bsum<<<1, 512, 0, stream>>>(bsum, NB);
  k_expand_add<<<NB, 256, 0, stream>>>(cursor, bsum, cntI, dstS, N);
  k_scatter_x<<<1024, 256, 0, stream>>>(ei, dts, cursor, srcdtS, E, N);
  prep_all<<<(N * 24 + 255) / 256, 256, 0, stream>>>(
      x, tW1, tW2, sW1, sW2, cW1, cW2, xb, W1t1, W2t1, W1t, W2t, cW1t, cW2t, N);

  // ---- phase 1 ----
  phase1_edge_mfma<<<1280, 256, 0, stream>>>(
      xb, dstS, srcdtS, freq, phs, W1t1, tb1, W2t1, tb2, acc1, E, nwt);
  phase1_node<<<(N + 3) / 4, 256, 0, stream>>>(x, acc1, cntI, pW, pb, h, acc2, N);

  // ---- phase 2: L = 2 message-passing + BN layers ----
  for (int l = 0; l < 2; l++) {
    float* bns = bnsAll + l * 128;
    float* bnq = bns + 64;
    prep_P<<<(N + 63) / 64, 256, 0, stream>>>(
        h, W1t + (size_t)l * 64 * 128, sb1 + l * 64, P1, P2, N);
    phase2_edge<<<1536, 256, 0, stream>>>(
        P1, P2, dstS, srcdtS, W2t + (size_t)l * 64 * 64, sb2 + l * 64,
        acc2, E, nwt);
    node_update_bn<<<1024, 256, 0, stream>>>(h, acc2, cntI, bns, bnq, N);
    bn_apply_relu<<<2048, 256, 0, stream>>>(
        h, bns, bnq, bng + l * 64, bnb + l * 64, N * 64, 63, 1.0f / (float)N);
  }

  // ---- classifier on first B rows of h (MFMA) ----
  const int CB = (B + 63) / 64;
  {
    float* bns = bnsAll + 256;   // slot 2 pair
    float* bnq = bns + 64;
    clf_mfma<4><<<CB, 256, 0, stream>>>(h, cW1t, cb1, z1, bns, bnq, B);
    bn_apply_relu<<<1024, 256, 0, stream>>>(z1, bns, bnq, cg1, cbb1,
                                            B * 64, 63, 1.0f / (float)B);
  }
  {
    float* bns = bnsAll + 384;   // slot 3 pair
    float* bnq = bns + 64;
    clf_mfma<2><<<CB, 256, 0, stream>>>(z1, cW2t, cb2, z2, bns, bnq, B);
    bn_apply_relu<<<512, 256, 0, stream>>>(z2, bns, bnq, cg2, cbb2,
                                           B * 32, 31, 1.0f / (float)B);
  }
  clf_final<<<(B + 255) / 256, 256, 0, stream>>>(z2, cW3, cb3, out, B);
}

// Round 15
// 914.915 us; speedup vs baseline: 1.0310x; 1.0310x over previous
//
#include <hip/hip_runtime.h>
#include <hip/hip_bf16.h>

// ---------------------------------------------------------------------------
// THEGCNModel — R15 (R13 binaries, bigger grids):
//   R14 evidence: tightening launch_bounds (256,5) re-triggered weight remat
//   (VGPR 64->48, FETCH 48->518MB). But launch_bounds' 2nd arg is a MINIMUM
//   guarantee, not a residency cap — R13's binaries already permit 5 (phase1,
//   LDS 28.2KB) and 8 (phase2, LDS 17.9KB) blocks/CU. So: keep R13's exact
//   bounds (256,3)/(256,4), raise ONLY the grids (768->1280, 1024->2048).
//   Keep R14's acc2-zero fold into phase1_node (one fewer 25.6MB memset).
// ---------------------------------------------------------------------------

typedef float  f32x4 __attribute__((ext_vector_type(4)));
typedef short  s16x8 __attribute__((ext_vector_type(8)));

__device__ __forceinline__ float tanh_factor(float u) {
  // 2*tanh(u)-1 == 1 - 4/(exp(2u)+1); rcp is 1-ulp approx (noise vs bf16)
  float e = __expf(2.0f * u);
  return fmaf(-4.0f, __builtin_amdgcn_rcpf(e + 1.0f), 1.0f);
}

__device__ __forceinline__ void atomic_add_f32(float* p, float v) {
  unsafeAtomicAdd(p, v);               // native global_atomic_add_f32
}

__device__ __forceinline__ unsigned short f2bf(float f) {
  __hip_bfloat16 b = __float2bfloat16(f);
  return *(unsigned short*)&b;
}
__device__ __forceinline__ float bf2f(unsigned short u) {
  unsigned int v = ((unsigned int)u) << 16;
  return *(float*)&v;
}

// ---------------------------------------------------------------------------
// Counting sort by dst: histogram -> scan -> expand(dstS) -> scatter(src,dts).
// ---------------------------------------------------------------------------
__global__ __launch_bounds__(256) void k_hist(
    const int* __restrict__ ei, int* __restrict__ cntI, int E)
{
  int e = blockIdx.x * 256 + threadIdx.x;
  if (e < E) atomicAdd(&cntI[__builtin_nontemporal_load(ei + E + e)], 1);
}

__global__ __launch_bounds__(256) void k_scan_block(
    const int* __restrict__ cntI, int* __restrict__ cursor,
    int* __restrict__ bsum, int N)
{
  __shared__ int s[256];
  const int t = threadIdx.x;
  int i = blockIdx.x * 256 + t;
  int v = (i < N) ? cntI[i] : 0;
  s[t] = v;
  for (int off = 1; off < 256; off <<= 1) {
    __syncthreads();
    int x = (t >= off) ? s[t - off] : 0;
    __syncthreads();
    s[t] += x;
  }
  __syncthreads();
  if (i < N) cursor[i] = s[t] - v;          // local exclusive
  if (t == 255) bsum[blockIdx.x] = s[255];
}

__global__ __launch_bounds__(512) void k_scan_bsum(int* __restrict__ bsum, int nb)
{
  __shared__ int s[512];
  const int t = threadIdx.x;
  int v = (t < nb) ? bsum[t] : 0;
  s[t] = v;
  for (int off = 1; off < 512; off <<= 1) {
    __syncthreads();
    int x = (t >= off) ? s[t - off] : 0;
    __syncthreads();
    s[t] += x;
  }
  __syncthreads();
  if (t < nb) bsum[t] = s[t] - v;           // exclusive
}

// fused: cursor += block offset (final rowPtr) AND expand dstS runs.
__global__ __launch_bounds__(256) void k_expand_add(
    int* __restrict__ cursor, const int* __restrict__ bsum,
    const int* __restrict__ cntI, int* __restrict__ dstS, int N)
{
  int n = blockIdx.x * 256 + threadIdx.x;
  if (n >= N) return;
  int cur = cursor[n] + bsum[blockIdx.x];
  cursor[n] = cur;
  int c = cntI[n];
  for (int i = 0; i < c; i++) dstS[cur + i] = n;
}

// XCD-partitioned scatter: group g = blockIdx&7 handles dst in [N*g/8,N*(g+1)/8)
// -> its srcdtS segment (~1.6MB) fits one XCD L2, lines fill fully.
__global__ __launch_bounds__(256) void k_scatter_x(
    const int* __restrict__ ei, const float* __restrict__ dts,
    int* __restrict__ cursor, int2* __restrict__ srcdtS, int E, int N)
{
  const int g  = blockIdx.x & 7;           // XCD proxy (round-robin heuristic)
  const int bi = blockIdx.x >> 3;
  const int nb = gridDim.x >> 3;
  const int lo = (int)(((long long)N * g) >> 3);
  const int hi = (int)(((long long)N * (g + 1)) >> 3);
  for (int e = bi * 256 + threadIdx.x; e < E; e += nb * 256) {
    int d = __builtin_nontemporal_load(ei + E + e);
    if (d >= lo && d < hi) {
      int s = __builtin_nontemporal_load(ei + e);
      float dt = __builtin_nontemporal_load(dts + e);
      int pos = atomicAdd(&cursor[d], 1);
      srcdtS[pos] = make_int2(s, __float_as_int(dt));
    }
  }
}

// ---------------------------------------------------------------------------
// prep_all: xb = bf16(x) padded to 24 cols; phase-1 weights W1t1/W2t1; phase-2
// weights W1t/W2t; classifier weights cW1t[c:64][k:64], cW2t[c:32][k:64].
// ---------------------------------------------------------------------------
__global__ __launch_bounds__(256) void prep_all(
    const float* __restrict__ x, const float* __restrict__ tW1,
    const float* __restrict__ tW2, const float* __restrict__ sW1,
    const float* __restrict__ sW2, const float* __restrict__ cW1,
    const float* __restrict__ cW2, unsigned short* __restrict__ xb,
    unsigned short* __restrict__ W1t1, unsigned short* __restrict__ W2t1,
    unsigned short* __restrict__ W1t, unsigned short* __restrict__ W2t,
    unsigned short* __restrict__ cW1t, unsigned short* __restrict__ cW2t, int N)
{
  int i = blockIdx.x * 256 + threadIdx.x;
  int totalX = N * 24;
  for (int idx = i; idx < totalX; idx += gridDim.x * 256) {
    int n = idx / 24, c = idx - n * 24;
    xb[idx] = (c < 17) ? f2bf(x[n * 17 + c]) : (unsigned short)0;
  }
  if (i < 48 * 96) {
    int n = i / 96, k = i - n * 96;
    int src = (k < 17) ? k : (k >= 24 && k < 41) ? (k - 24 + 17)
            : (k >= 48 && k < 80) ? (k - 48 + 34) : -1;
    W1t1[i] = (n < 33 && src >= 0) ? f2bf(tW1[src * 33 + n]) : (unsigned short)0;
  }
  if (i < 32 * 64) {
    int n = i / 64, k = i - n * 64;
    W2t1[i] = (n < 17 && k < 33) ? f2bf(tW2[k * 17 + n]) : (unsigned short)0;
  }
  if (i < 2 * 64 * 128) {
    int l = i >> 13; int r = i & 8191; int n = r >> 7; int k = r & 127;
    W1t[i] = f2bf(sW1[((size_t)l * 128 + k) * 64 + n]);
  }
  if (i < 2 * 64 * 64) {
    int l = i >> 12; int r = i & 4095; int n = r >> 6; int k = r & 63;
    W2t[i] = f2bf(sW2[((size_t)l * 64 + k) * 64 + n]);
  }
  if (i < 64 * 64) {
    int c = i >> 6, k = i & 63;
    cW1t[i] = f2bf(cW1[k * 64 + c]);
  }
  if (i < 32 * 64) {
    int c = i >> 6, k = i & 63;
    cW2t[i] = f2bf(cW2[k * 32 + c]);
  }
}

// ---------------------------------------------------------------------------
// Phase 1 edge kernel (MFMA, barrier-free wave-private 16-edge tiles).
// bounds(256,3) — DO NOT TIGHTEN: R6/R7/R14 showed any tighter cap makes the
// compiler rematerialize weight frags from global each tile (FETCH 10x).
// Occupancy comes from the grid: VGPR 64 / LDS 28.2KB permit 5 blocks/CU.
// ---------------------------------------------------------------------------
__global__ __launch_bounds__(256, 3) void phase1_edge_mfma(
    const unsigned short* __restrict__ xb, const int* __restrict__ dstS,
    const int2* __restrict__ srcdtS, const float* __restrict__ freq,
    const float* __restrict__ phs,
    const unsigned short* __restrict__ W1t1, const float* __restrict__ b1,
    const unsigned short* __restrict__ W2t1, const float* __restrict__ b2,
    float* __restrict__ accum, int E, int nwt)
{
  __shared__ unsigned short sA[64][104];
  __shared__ unsigned short sHid[64][72];
  __shared__ float sRed[64][20];
  __shared__ int   sDst[64];

  const int t = threadIdx.x;
  const int wv = t >> 6, lane = t & 63, l16 = lane & 15, quad = lane >> 4;
  const int r0 = wv * 16;

  s16x8 w1f[3][3], w2f[2][2];
  float bias1[3], bias2[2];
#pragma unroll
  for (int cb = 0; cb < 3; cb++) {
    int n = cb * 16 + l16;
#pragma unroll
    for (int kb = 0; kb < 3; kb++)
      w1f[cb][kb] = *(const s16x8*)&W1t1[n * 96 + kb * 32 + quad * 8];
    bias1[cb] = (n < 33) ? b1[n] : 0.0f;
  }
#pragma unroll
  for (int cb = 0; cb < 2; cb++) {
    int n = cb * 16 + l16;
#pragma unroll
    for (int kb = 0; kb < 2; kb++)
      w2f[cb][kb] = *(const s16x8*)&W2t1[n * 64 + kb * 32 + quad * 8];
    bias2[cb] = (n < 17) ? b2[n] : 0.0f;
  }

  // zero own-wave pad columns once
  for (int i = lane; i < 16 * 28; i += 64) {
    int rr = r0 + i / 28, c = i % 28;
    int col = (c < 6) ? 18 + c : (c < 12) ? 42 + (c - 6) : 80 + (c - 12);
    sA[rr][col] = 0;
  }
  for (int i = lane; i < 256; i += 64)
    sHid[r0 + (i >> 4)][48 + (i & 15)] = 0;

  const int gw = blockIdx.x * 4 + wv;
  const int nw = gridDim.x * 4;

  for (int tile = gw; tile < nwt; tile += nw) {
    const int eb = tile << 4;

    // staging: 4 lanes/edge (q0 xi, q1 xj, q2/q3 rel halves) — own rows only
    {
      int e_loc = lane >> 2, q = lane & 3;
      int rr = r0 + e_loc;
      int er = eb + e_loc; if (er >= E) er = E - 1;
      if (q < 2) {
        int node = q ? srcdtS[er].x : dstS[er];
        if (!q) sDst[rr] = node;
        const unsigned short* src = &xb[(size_t)node * 24];
        int base = q ? 24 : 0;
        *(uint4*)&sA[rr][base]     = *(const uint4*)&src[0];
        *(uint4*)&sA[rr][base + 8] = *(const uint4*)&src[8];
        *(unsigned int*)&sA[rr][base + 16] = *(const unsigned int*)&src[16];
      } else {
        float dt = __int_as_float(srcdtS[er].y);
        int k0 = (q == 2) ? 0 : 16;
        unsigned short tmp[16] __attribute__((aligned(16)));
#pragma unroll
        for (int j = 0; j < 16; j++)
          tmp[j] = f2bf(__cosf(fmaf(dt, freq[k0 + j], phs[k0 + j])));
        *(uint4*)&sA[rr][48 + k0]     = *(const uint4*)&tmp[0];
        *(uint4*)&sA[rr][48 + k0 + 8] = *(const uint4*)&tmp[8];
      }
    }

    // pass1: hid = relu(A @ W1 + b1)   (own row r0+l16)
    f32x4 a1[3];
#pragma unroll
    for (int cb = 0; cb < 3; cb++)
      a1[cb] = (f32x4){bias1[cb], bias1[cb], bias1[cb], bias1[cb]};
#pragma unroll
    for (int kb = 0; kb < 3; kb++) {
      s16x8 aF = *(const s16x8*)&sA[r0 + l16][kb * 32 + quad * 8];
#pragma unroll
      for (int cb = 0; cb < 3; cb++)
        a1[cb] = __builtin_amdgcn_mfma_f32_16x16x32_bf16(aF, w1f[cb][kb], a1[cb], 0, 0, 0);
    }
#pragma unroll
    for (int cb = 0; cb < 3; cb++)
#pragma unroll
      for (int reg = 0; reg < 4; reg++)
        sHid[r0 + quad * 4 + reg][cb * 16 + l16] = f2bf(fmaxf(a1[cb][reg], 0.0f));

    // pass2: u = hid @ W2 + b2
    f32x4 a2[2];
#pragma unroll
    for (int cb = 0; cb < 2; cb++)
      a2[cb] = (f32x4){bias2[cb], bias2[cb], bias2[cb], bias2[cb]};
#pragma unroll
    for (int kb = 0; kb < 2; kb++) {
      s16x8 aF = *(const s16x8*)&sHid[r0 + l16][kb * 32 + quad * 8];
#pragma unroll
      for (int cb = 0; cb < 2; cb++)
        a2[cb] = __builtin_amdgcn_mfma_f32_16x16x32_bf16(aF, w2f[cb][kb], a2[cb], 0, 0, 0);
    }

    // f -> sRed (own rows)
#pragma unroll
    for (int reg = 0; reg < 4; reg++) {
      int row = r0 + quad * 4 + reg;
      bool ok = (eb + quad * 4 + reg < E);
      sRed[row][l16] = ok ? tanh_factor(a2[0][reg]) : 0.0f;
      if (l16 == 0) sRed[row][16] = ok ? tanh_factor(a2[1][reg]) : 0.0f;
    }

    // wave-local segmented walk: lanes 0..16, col = lane, own 16 rows
    if (lane < 17) {
      int col = lane;
      float run = 0.0f;
      int cur = sDst[r0];
#pragma unroll
      for (int k = 0; k < 16; k++) {
        int d = sDst[r0 + k];
        float v = sRed[r0 + k][col];
        if (d != cur) {
          atomic_add_f32(&accum[(size_t)cur * 17 + col], run);
          run = 0.0f; cur = d;
        }
        run += v;
      }
      atomic_add_f32(&accum[(size_t)cur * 17 + col], run);
    }
  }
}

// ---------------------------------------------------------------------------
// Phase 1 node kernel: h[n] = (x[n] * (1 + acc/max(cnt,1))) @ projW + projb.
// Also zeroes acc2 (replaces a 25.6MB memset dispatch).
// ---------------------------------------------------------------------------
__global__ __launch_bounds__(256) void phase1_node(
    const float* __restrict__ x, const float* __restrict__ acc1,
    const int* __restrict__ cntI, const float* __restrict__ Wp,
    const float* __restrict__ bp, float* __restrict__ h,
    float* __restrict__ acc2, int N)
{
  __shared__ float s0[4][20];
  const int t = threadIdx.x;
  const int nb = blockIdx.x << 2;
  if (t < 68) {
    int nl = t / 17, c = t % 17;
    int n = nb + nl;
    float v = 0.0f;
    if (n < N) {
      float cnt = fmaxf((float)cntI[n], 1.0f);
      v = x[n * 17 + c] * (1.0f + acc1[n * 17 + c] / cnt);
    }
    s0[nl][c] = v;
  }
  __syncthreads();
  int nl = t >> 6, j = t & 63;
  int n = nb + nl;
  if (n < N) {
    float acc = bp[j];
#pragma unroll
    for (int c = 0; c < 17; c++) acc = fmaf(s0[nl][c], Wp[c * 64 + j], acc);
    h[n * 64 + j] = acc;
    acc2[n * 64 + j] = 0.0f;
  }
}

// ---------------------------------------------------------------------------
// prep_P: P1[n] = h[n]@W1a + b1, P2[n] = h[n]@W1b (dense per-node, MFMA).
// ---------------------------------------------------------------------------
__global__ void prep_P(
    const float* __restrict__ h, const unsigned short* __restrict__ W1t,
    const float* __restrict__ b1, unsigned short* __restrict__ P1,
    unsigned short* __restrict__ P2, int N)
{
  __shared__ unsigned short sH[64][72];
  const int t = threadIdx.x;
  const int wv = t >> 6, lane = t & 63, l16 = lane & 15, quad = lane >> 4;
  const int nb = blockIdx.x << 6;

#pragma unroll
  for (int i = 0; i < 4; i++) {
    int g = t + i * 256;
    int r = g >> 4, c4 = (g & 15) << 2;
    int n = nb + r; if (n >= N) n = N - 1;
    float4 v = *(const float4*)&h[(size_t)n * 64 + c4];
    ushort4 o = { f2bf(v.x), f2bf(v.y), f2bf(v.z), f2bf(v.w) };
    *(ushort4*)&sH[r][c4] = o;
  }
  __syncthreads();

  const int n = nb + wv * 16 + l16;
#pragma unroll
  for (int half = 0; half < 2; half++) {
    f32x4 acc[4];
#pragma unroll
    for (int cb = 0; cb < 4; cb++) {
      if (half == 0) {
        float4 bv = *(const float4*)&b1[cb * 16 + quad * 4];
        acc[cb] = (f32x4){bv.x, bv.y, bv.z, bv.w};
      } else {
        acc[cb] = (f32x4){0.0f, 0.0f, 0.0f, 0.0f};
      }
    }
#pragma unroll
    for (int kb = 0; kb < 2; kb++) {
      s16x8 bF = *(const s16x8*)&sH[wv * 16 + l16][kb * 32 + quad * 8];
#pragma unroll
      for (int cb = 0; cb < 4; cb++) {
        s16x8 aF = *(const s16x8*)&W1t[(cb * 16 + l16) * 128 + half * 64 + kb * 32 + quad * 8];
        acc[cb] = __builtin_amdgcn_mfma_f32_16x16x32_bf16(aF, bF, acc[cb], 0, 0, 0);
      }
    }
    if (n < N) {
      unsigned short* P = half ? P2 : P1;
#pragma unroll
      for (int cb = 0; cb < 4; cb++) {
        ushort4 o = { f2bf(acc[cb][0]), f2bf(acc[cb][1]),
                      f2bf(acc[cb][2]), f2bf(acc[cb][3]) };
        *(ushort4*)&P[(size_t)n * 64 + cb * 16 + quad * 4] = o;
      }
    }
  }
}

// ---------------------------------------------------------------------------
// Phase 2 edge kernel — barrier-free wave-private 16-edge tiles.
// bounds(256,4) — DO NOT TIGHTEN (see phase1 note). VGPR 52 / LDS 17.9KB
// permit 8 blocks/CU; grid 2048 delivers it.
// ---------------------------------------------------------------------------
__global__ __launch_bounds__(256, 4) void phase2_edge(
    const unsigned short* __restrict__ P1, const unsigned short* __restrict__ P2,
    const int* __restrict__ dstS, const int2* __restrict__ srcdtS,
    const unsigned short* __restrict__ W2t, const float* __restrict__ b2,
    float* __restrict__ accum, int E, int nwt)
{
  __shared__ unsigned short sA[64][136];   // [edge][0:64]=P1[dst], [64:128]=P2[src]
  __shared__ int sDst[64];
  float* sRedF = (float*)&sA[0][0];        // aliased 64x68 f32 (same stride 272B)

  const int t = threadIdx.x;
  const int wv = t >> 6, lane = t & 63, l16 = lane & 15, quad = lane >> 4;
  const int r0 = wv * 16;

  s16x8 w2f[4][2];
  f32x4 bias2v[4];
#pragma unroll
  for (int cb = 0; cb < 4; cb++) {
#pragma unroll
    for (int kb = 0; kb < 2; kb++)
      w2f[cb][kb] = *(const s16x8*)&W2t[(cb * 16 + l16) * 64 + kb * 32 + quad * 8];
    float4 bv = *(const float4*)&b2[cb * 16 + quad * 4];
    bias2v[cb] = (f32x4){bv.x, bv.y, bv.z, bv.w};
  }

  const int gw = blockIdx.x * 4 + wv;
  const int nw = gridDim.x * 4;
  const int eRow = r0 + l16;

  for (int tile = gw; tile < nwt; tile += nw) {
    const int eb = tile << 4;

    // staging: 4 lanes/edge, 64B contiguous per lane, own rows only
    {
      int e_loc = lane >> 2, q = lane & 3;
      int rr = r0 + e_loc;
      int er = eb + e_loc; if (er >= E) er = E - 1;
      int node;
      if (q < 2) { node = dstS[er]; if (!q) sDst[rr] = node; }
      else       node = srcdtS[er].x;
      const unsigned short* src = (q < 2 ? P1 : P2) + (size_t)node * 64 + (q & 1) * 32;
      int cb0 = q * 32;
#pragma unroll
      for (int j = 0; j < 4; j++)
        *(uint4*)&sA[rr][cb0 + j * 8] = *(const uint4*)&src[j * 8];
    }

    // hidden B-frags: relu(P1+P2), packed bf16 (own row)
    s16x8 hidf[2];
#pragma unroll
    for (int kb = 0; kb < 2; kb++) {
      s16x8 x1 = *(const s16x8*)&sA[eRow][kb * 32 + quad * 8];
      s16x8 x2 = *(const s16x8*)&sA[eRow][64 + kb * 32 + quad * 8];
      s16x8 hf;
#pragma unroll
      for (int j = 0; j < 8; j++) {
        float a = bf2f((unsigned short)x1[j]);
        float b = bf2f((unsigned short)x2[j]);
        hf[j] = (short)f2bf(fmaxf(a + b, 0.0f));
      }
      hidf[kb] = hf;
    }

    // u^T[n2][edge] = W2t @ hidden^T + b2
    f32x4 acc[4];
#pragma unroll
    for (int cb = 0; cb < 4; cb++) acc[cb] = bias2v[cb];
#pragma unroll
    for (int kb = 0; kb < 2; kb++)
#pragma unroll
      for (int cb = 0; cb < 4; cb++)
        acc[cb] = __builtin_amdgcn_mfma_f32_16x16x32_bf16(w2f[cb][kb], hidf[kb], acc[cb], 0, 0, 0);

    // f = 2*tanh(u)-1 -> sRedF (own rows; same-wave ordering)
    bool ok = (eb + l16 < E);
#pragma unroll
    for (int cb = 0; cb < 4; cb++) {
      f32x4 f;
#pragma unroll
      for (int reg = 0; reg < 4; reg++)
        f[reg] = ok ? tanh_factor(acc[cb][reg]) : 0.0f;
      *(f32x4*)&sRedF[eRow * 68 + cb * 16 + quad * 4] = f;
    }

    // wave-local segmented walk: lane = col, own 16 rows
    {
      float run = 0.0f;
      int cur = sDst[r0];
#pragma unroll
      for (int k = 0; k < 16; k++) {
        int d = sDst[r0 + k];                 // wave-uniform
        float v = sRedF[(r0 + k) * 68 + lane];
        if (d != cur) {                       // wave-uniform branch
          atomic_add_f32(&accum[(size_t)cur * 64 + lane], run);
          run = 0.0f; cur = d;
        }
        run += v;
      }
      atomic_add_f32(&accum[(size_t)cur * 64 + lane], run);
    }
  }
}

// ---------------------------------------------------------------------------
// Node update + BN statistics; re-zeroes accum for the next layer.
// ---------------------------------------------------------------------------
__global__ __launch_bounds__(256) void node_update_bn(
    float* __restrict__ h, float* __restrict__ accum,
    const int* __restrict__ cntI, float* __restrict__ bns,
    float* __restrict__ bnq, int N)
{
  const int t = threadIdx.x;
  float ls = 0.0f, lq = 0.0f;
  int total = N * 64;
  for (int idx = blockIdx.x * 256 + t; idx < total; idx += gridDim.x * 256) {
    int n = idx >> 6;
    float cnt = fmaxf((float)cntI[n], 1.0f);
    float v = h[idx] * (1.0f + accum[idx] / cnt);
    accum[idx] = 0.0f;                 // ready for next layer's scatter
    h[idx] = v;
    ls += v; lq += v * v;
  }
  __shared__ float ss[256], sq[256];
  ss[t] = ls; sq[t] = lq;
  __syncthreads();
  if (t < 64) {
    float s = ss[t] + ss[t + 64] + ss[t + 128] + ss[t + 192];
    float q = sq[t] + sq[t + 64] + sq[t + 128] + sq[t + 192];
    atomic_add_f32(&bns[t], s);
    atomic_add_f32(&bnq[t], q);
  }
}

// ---------------------------------------------------------------------------
// BN apply + relu (in place).
// ---------------------------------------------------------------------------
__global__ __launch_bounds__(256) void bn_apply_relu(
    float* __restrict__ d, const float* __restrict__ bns,
    const float* __restrict__ bnq, const float* __restrict__ gam,
    const float* __restrict__ bet, int total, int cmask, float invRows)
{
  for (int idx = blockIdx.x * 256 + threadIdx.x; idx < total;
       idx += gridDim.x * 256) {
    int c = idx & cmask;
    float m = bns[c] * invRows;
    float var = bnq[c] * invRows - m * m;
    float sc = gam[c] * rsqrtf(var + 1e-5f);
    d[idx] = fmaxf((d[idx] - m) * sc + bet[c], 0.0f);
  }
}

// ---------------------------------------------------------------------------
// Classifier MFMA (prep_P operand-swap pattern, K=64, COUT = NCB*16):
// z[n][c] f32 + fused BN stats (shfl-reduce over l16 rows, atomic per col).
// ---------------------------------------------------------------------------
template <int NCB>
__global__ __launch_bounds__(256) void clf_mfma(
    const float* __restrict__ in, const unsigned short* __restrict__ Wt,
    const float* __restrict__ bias, float* __restrict__ z,
    float* __restrict__ bns, float* __restrict__ bnq, int rows)
{
  __shared__ unsigned short sIn[64][72];
  const int t = threadIdx.x;
  const int wv = t >> 6, lane = t & 63, l16 = lane & 15, quad = lane >> 4;
  const int nb = blockIdx.x << 6;

  s16x8 wf[NCB][2];
  f32x4 bv[NCB];
#pragma unroll
  for (int cb = 0; cb < NCB; cb++) {
#pragma unroll
    for (int kb = 0; kb < 2; kb++)
      wf[cb][kb] = *(const s16x8*)&Wt[(cb * 16 + l16) * 64 + kb * 32 + quad * 8];
    float4 b4 = *(const float4*)&bias[cb * 16 + quad * 4];
    bv[cb] = (f32x4){b4.x, b4.y, b4.z, b4.w};
  }

#pragma unroll
  for (int i = 0; i < 4; i++) {
    int g = t + i * 256;
    int r = g >> 4, c4 = (g & 15) << 2;
    int n = nb + r; if (n >= rows) n = rows - 1;
    float4 v = *(const float4*)&in[(size_t)n * 64 + c4];
    ushort4 o = { f2bf(v.x), f2bf(v.y), f2bf(v.z), f2bf(v.w) };
    *(ushort4*)&sIn[r][c4] = o;
  }
  __syncthreads();

  const int n = nb + wv * 16 + l16;
  const bool ok = (n < rows);
  f32x4 acc[NCB];
#pragma unroll
  for (int cb = 0; cb < NCB; cb++) acc[cb] = bv[cb];
#pragma unroll
  for (int kb = 0; kb < 2; kb++) {
    s16x8 bF = *(const s16x8*)&sIn[wv * 16 + l16][kb * 32 + quad * 8];
#pragma unroll
    for (int cb = 0; cb < NCB; cb++)
      acc[cb] = __builtin_amdgcn_mfma_f32_16x16x32_bf16(wf[cb][kb], bF, acc[cb], 0, 0, 0);
  }

  // store z (f32) + per-col stats reduced over the wave's 16 rows
#pragma unroll
  for (int cb = 0; cb < NCB; cb++) {
    if (ok)
      *(float4*)&z[(size_t)n * (NCB * 16) + cb * 16 + quad * 4] =
          make_float4(acc[cb][0], acc[cb][1], acc[cb][2], acc[cb][3]);
    f32x4 s, q;
#pragma unroll
    for (int reg = 0; reg < 4; reg++) {
      float v = ok ? acc[cb][reg] : 0.0f;
      s[reg] = v; q[reg] = v * v;
    }
#pragma unroll
    for (int m = 1; m < 16; m <<= 1) {
#pragma unroll
      for (int reg = 0; reg < 4; reg++) {
        s[reg] += __shfl_xor(s[reg], m);
        q[reg] += __shfl_xor(q[reg], m);
      }
    }
    if (l16 == 0) {
#pragma unroll
      for (int reg = 0; reg < 4; reg++) {
        int col = cb * 16 + quad * 4 + reg;
        atomic_add_f32(&bns[col], s[reg]);
        atomic_add_f32(&bnq[col], q[reg]);
      }
    }
  }
}

__global__ __launch_bounds__(256) void clf_final(
    const float* __restrict__ z2, const float* __restrict__ W3,
    const float* __restrict__ b3, float* __restrict__ out, int rows)
{
  int n = blockIdx.x * 256 + threadIdx.x;
  if (n >= rows) return;
  float acc = b3[0];
#pragma unroll
  for (int k = 0; k < 32; k++) acc = fmaf(z2[n * 32 + k], W3[k], acc);
  out[n] = acc;
}

// ---------------------------------------------------------------------------
extern "C" void kernel_launch(void* const* d_in, const int* in_sizes, int n_in,
                              void* d_out, int out_size, void* d_ws, size_t ws_size,
                              hipStream_t stream)
{
  const float* x    = (const float*)d_in[0];
  const int*   ei   = (const int*)  d_in[1];
  const float* dts  = (const float*)d_in[2];
  const float* freq = (const float*)d_in[4];
  const float* phs  = (const float*)d_in[5];
  const float* tW1  = (const float*)d_in[6];
  const float* tb1  = (const float*)d_in[7];
  const float* tW2  = (const float*)d_in[8];
  const float* tb2  = (const float*)d_in[9];
  const float* pW   = (const float*)d_in[10];
  const float* pb   = (const float*)d_in[11];
  const float* sW1  = (const float*)d_in[12];
  const float* sb1  = (const float*)d_in[13];
  const float* sW2  = (const float*)d_in[14];
  const float* sb2  = (const float*)d_in[15];
  const float* bng  = (const float*)d_in[16];
  const float* bnb  = (const float*)d_in[17];
  const float* cW1  = (const float*)d_in[18];
  const float* cb1  = (const float*)d_in[19];
  const float* cg1  = (const float*)d_in[20];
  const float* cbb1 = (const float*)d_in[21];
  const float* cW2  = (const float*)d_in[22];
  const float* cb2  = (const float*)d_in[23];
  const float* cg2  = (const float*)d_in[24];
  const float* cbb2 = (const float*)d_in[25];
  const float* cW3  = (const float*)d_in[26];
  const float* cb3  = (const float*)d_in[27];
  float* out = (float*)d_out;

  const int N = in_sizes[0] / 17;
  const int E = in_sizes[1] / 2;
  const int B = out_size;

  // ---- workspace layout (byte offsets, union region for phase-local data) --
  char* base = (char*)d_ws;
  size_t off = 0;
  float* h    = (float*)(base + off); off += (size_t)N * 64 * 4;
  float* acc2 = (float*)(base + off); off += (size_t)N * 64 * 4;
  char*  uni  = base + off;           off += (size_t)N * 64 * 4;  // union
  float* bnsAll = (float*)(base + off); off += 8 * 64 * 4;        // 8 slots
  unsigned short* W1t = (unsigned short*)(base + off); off += 2 * 64 * 128 * 2;
  unsigned short* W2t = (unsigned short*)(base + off); off += 2 * 64 * 64 * 2;
  unsigned short* cW1t = (unsigned short*)(base + off); off += 64 * 64 * 2;
  unsigned short* cW2t = (unsigned short*)(base + off); off += 32 * 64 * 2;
  int* cntI   = (int*)(base + off); off += (size_t)N * 4;
  int* cursor = (int*)(base + off); off += (size_t)N * 4;
  int* bsum   = (int*)(base + off); off += 512 * 4;
  int* dstS   = (int*)(base + off); off += (size_t)E * 4;
  off = (off + 15) & ~(size_t)15;
  int2* srcdtS = (int2*)(base + off); off += (size_t)E * 8;
  size_t needed = off;
  if (ws_size < needed) return;  // fail visibly (output stays poisoned)

  // union members (phase1 | phase2 | classifier — lifetimes disjoint)
  float* acc1 = (float*)uni;                                     // N*17 f32
  unsigned short* xb   = (unsigned short*)(uni + (size_t)N * 17 * 4); // N*24
  unsigned short* W1t1 = xb + (size_t)N * 24;                    // 48*96
  unsigned short* W2t1 = W1t1 + 48 * 96;                         // 32*64
  unsigned short* P1 = (unsigned short*)uni;                     // N*64
  unsigned short* P2 = P1 + (size_t)N * 64;                      // N*64
  float* z1 = (float*)uni;                                       // B*64
  float* z2 = z1 + (size_t)B * 64;                               // B*32

  const int nwt = (E + 15) / 16;
  const int NB = (N + 255) / 256;
  if (NB > 512) return;

  // ---- init (poisoned ws): counts, acc1, BN-stat slots ----
  hipMemsetAsync(cntI, 0, (size_t)N * 4, stream);
  hipMemsetAsync(acc1, 0, (size_t)N * 17 * 4, stream);
  hipMemsetAsync(bnsAll, 0, 8 * 64 * 4, stream);

  // ---- counting sort by dst (yields counts + dstS) + weight/x prep ----
  k_hist<<<(E + 255) / 256, 256, 0, stream>>>(ei, cntI, E);
  k_scan_block<<<NB, 256, 0, stream>>>(cntI, cursor, bsum, N);
  k_scan_bsum<<<1, 512, 0, stream>>>(bsum, NB);
  k_expand_add<<<NB, 256, 0, stream>>>(cursor, bsum, cntI, dstS, N);
  k_scatter_x<<<1024, 256, 0, stream>>>(ei, dts, cursor, srcdtS, E, N);
  prep_all<<<(N * 24 + 255) / 256, 256, 0, stream>>>(
      x, tW1, tW2, sW1, sW2, cW1, cW2, xb, W1t1, W2t1, W1t, W2t, cW1t, cW2t, N);

  // ---- phase 1 (grid 1280 = 5 blocks/CU; binary unchanged from R13) ----
  phase1_edge_mfma<<<1280, 256, 0, stream>>>(
      xb, dstS, srcdtS, freq, phs, W1t1, tb1, W2t1, tb2, acc1, E, nwt);
  phase1_node<<<(N + 3) / 4, 256, 0, stream>>>(x, acc1, cntI, pW, pb, h, acc2, N);

  // ---- phase 2: L = 2 message-passing + BN layers (grid 2048 = 8 blk/CU) --
  for (int l = 0; l < 2; l++) {
    float* bns = bnsAll + l * 128;
    float* bnq = bns + 64;
    prep_P<<<(N + 63) / 64, 256, 0, stream>>>(
        h, W1t + (size_t)l * 64 * 128, sb1 + l * 64, P1, P2, N);
    phase2_edge<<<2048, 256, 0, stream>>>(
        P1, P2, dstS, srcdtS, W2t + (size_t)l * 64 * 64, sb2 + l * 64,
        acc2, E, nwt);
    node_update_bn<<<1024, 256, 0, stream>>>(h, acc2, cntI, bns, bnq, N);
    bn_apply_relu<<<2048, 256, 0, stream>>>(
        h, bns, bnq, bng + l * 64, bnb + l * 64, N * 64, 63, 1.0f / (float)N);
  }

  // ---- classifier on first B rows of h (MFMA) ----
  const int CB = (B + 63) / 64;
  {
    float* bns = bnsAll + 256;   // slot 2 pair
    float* bnq = bns + 64;
    clf_mfma<4><<<CB, 256, 0, stream>>>(h, cW1t, cb1, z1, bns, bnq, B);
    bn_apply_relu<<<1024, 256, 0, stream>>>(z1, bns, bnq, cg1, cbb1,
                                            B * 64, 63, 1.0f / (float)B);
  }
  {
    float* bns = bnsAll + 384;   // slot 3 pair
    float* bnq = bns + 64;
    clf_mfma<2><<<CB, 256, 0, stream>>>(z1, cW2t, cb2, z2, bns, bnq, B);
    bn_apply_relu<<<512, 256, 0, stream>>>(z2, bns, bnq, cg2, cbb2,
                                           B * 32, 31, 1.0f / (float)B);
  }
  clf_final<<<(B + 255) / 256, 256, 0, stream>>>(z2, cW3, cb3, out, B);
}

// Round 16
// 868.620 us; speedup vs baseline: 1.0859x; 1.0533x over previous
//
#include <hip/hip_runtime.h>
#include <hip/hip_bf16.h>

// ---------------------------------------------------------------------------
// THEGCNModel — R16 (R13 config + BN fused into consumers):
//   * Edge kernels: EXACT R13 config — bounds(256,3)/(256,4), grids 768/1024.
//     R14 (tighter bounds -> remat, FETCH 10x) and R15 (bigger grid -> occ
//     unchanged, dur +15%) both regressed: R13 is a sharp local optimum.
//   * All 4 bn_apply_relu passes removed; BN applied in the consumer's
//     staging: prep_P<true> (l=1, writes post-BN h back), clf_mfma<4> (only
//     B rows — skips a 51MB full-N pass), clf_mfma<2>, clf_final.
// ---------------------------------------------------------------------------

typedef float  f32x4 __attribute__((ext_vector_type(4)));
typedef short  s16x8 __attribute__((ext_vector_type(8)));

__device__ __forceinline__ float tanh_factor(float u) {
  // 2*tanh(u)-1 == 1 - 4/(exp(2u)+1); rcp is 1-ulp approx (noise vs bf16)
  float e = __expf(2.0f * u);
  return fmaf(-4.0f, __builtin_amdgcn_rcpf(e + 1.0f), 1.0f);
}

__device__ __forceinline__ void atomic_add_f32(float* p, float v) {
  unsafeAtomicAdd(p, v);               // native global_atomic_add_f32
}

__device__ __forceinline__ unsigned short f2bf(float f) {
  __hip_bfloat16 b = __float2bfloat16(f);
  return *(unsigned short*)&b;
}
__device__ __forceinline__ float bf2f(unsigned short u) {
  unsigned int v = ((unsigned int)u) << 16;
  return *(float*)&v;
}

// ---------------------------------------------------------------------------
// Counting sort by dst: histogram -> scan -> expand(dstS) -> scatter(src,dts).
// ---------------------------------------------------------------------------
__global__ __launch_bounds__(256) void k_hist(
    const int* __restrict__ ei, int* __restrict__ cntI, int E)
{
  int e = blockIdx.x * 256 + threadIdx.x;
  if (e < E) atomicAdd(&cntI[__builtin_nontemporal_load(ei + E + e)], 1);
}

__global__ __launch_bounds__(256) void k_scan_block(
    const int* __restrict__ cntI, int* __restrict__ cursor,
    int* __restrict__ bsum, int N)
{
  __shared__ int s[256];
  const int t = threadIdx.x;
  int i = blockIdx.x * 256 + t;
  int v = (i < N) ? cntI[i] : 0;
  s[t] = v;
  for (int off = 1; off < 256; off <<= 1) {
    __syncthreads();
    int x = (t >= off) ? s[t - off] : 0;
    __syncthreads();
    s[t] += x;
  }
  __syncthreads();
  if (i < N) cursor[i] = s[t] - v;          // local exclusive
  if (t == 255) bsum[blockIdx.x] = s[255];
}

__global__ __launch_bounds__(512) void k_scan_bsum(int* __restrict__ bsum, int nb)
{
  __shared__ int s[512];
  const int t = threadIdx.x;
  int v = (t < nb) ? bsum[t] : 0;
  s[t] = v;
  for (int off = 1; off < 512; off <<= 1) {
    __syncthreads();
    int x = (t >= off) ? s[t - off] : 0;
    __syncthreads();
    s[t] += x;
  }
  __syncthreads();
  if (t < nb) bsum[t] = s[t] - v;           // exclusive
}

// fused: cursor += block offset (final rowPtr) AND expand dstS runs.
__global__ __launch_bounds__(256) void k_expand_add(
    int* __restrict__ cursor, const int* __restrict__ bsum,
    const int* __restrict__ cntI, int* __restrict__ dstS, int N)
{
  int n = blockIdx.x * 256 + threadIdx.x;
  if (n >= N) return;
  int cur = cursor[n] + bsum[blockIdx.x];
  cursor[n] = cur;
  int c = cntI[n];
  for (int i = 0; i < c; i++) dstS[cur + i] = n;
}

// XCD-partitioned scatter: group g = blockIdx&7 handles dst in [N*g/8,N*(g+1)/8)
// -> its srcdtS segment (~1.6MB) fits one XCD L2, lines fill fully.
__global__ __launch_bounds__(256) void k_scatter_x(
    const int* __restrict__ ei, const float* __restrict__ dts,
    int* __restrict__ cursor, int2* __restrict__ srcdtS, int E, int N)
{
  const int g  = blockIdx.x & 7;           // XCD proxy (round-robin heuristic)
  const int bi = blockIdx.x >> 3;
  const int nb = gridDim.x >> 3;
  const int lo = (int)(((long long)N * g) >> 3);
  const int hi = (int)(((long long)N * (g + 1)) >> 3);
  for (int e = bi * 256 + threadIdx.x; e < E; e += nb * 256) {
    int d = __builtin_nontemporal_load(ei + E + e);
    if (d >= lo && d < hi) {
      int s = __builtin_nontemporal_load(ei + e);
      float dt = __builtin_nontemporal_load(dts + e);
      int pos = atomicAdd(&cursor[d], 1);
      srcdtS[pos] = make_int2(s, __float_as_int(dt));
    }
  }
}

// ---------------------------------------------------------------------------
// prep_all: xb = bf16(x) padded to 24 cols; phase-1 weights W1t1/W2t1; phase-2
// weights W1t/W2t; classifier weights cW1t[c:64][k:64], cW2t[c:32][k:64].
// ---------------------------------------------------------------------------
__global__ __launch_bounds__(256) void prep_all(
    const float* __restrict__ x, const float* __restrict__ tW1,
    const float* __restrict__ tW2, const float* __restrict__ sW1,
    const float* __restrict__ sW2, const float* __restrict__ cW1,
    const float* __restrict__ cW2, unsigned short* __restrict__ xb,
    unsigned short* __restrict__ W1t1, unsigned short* __restrict__ W2t1,
    unsigned short* __restrict__ W1t, unsigned short* __restrict__ W2t,
    unsigned short* __restrict__ cW1t, unsigned short* __restrict__ cW2t, int N)
{
  int i = blockIdx.x * 256 + threadIdx.x;
  int totalX = N * 24;
  for (int idx = i; idx < totalX; idx += gridDim.x * 256) {
    int n = idx / 24, c = idx - n * 24;
    xb[idx] = (c < 17) ? f2bf(x[n * 17 + c]) : (unsigned short)0;
  }
  if (i < 48 * 96) {
    int n = i / 96, k = i - n * 96;
    int src = (k < 17) ? k : (k >= 24 && k < 41) ? (k - 24 + 17)
            : (k >= 48 && k < 80) ? (k - 48 + 34) : -1;
    W1t1[i] = (n < 33 && src >= 0) ? f2bf(tW1[src * 33 + n]) : (unsigned short)0;
  }
  if (i < 32 * 64) {
    int n = i / 64, k = i - n * 64;
    W2t1[i] = (n < 17 && k < 33) ? f2bf(tW2[k * 17 + n]) : (unsigned short)0;
  }
  if (i < 2 * 64 * 128) {
    int l = i >> 13; int r = i & 8191; int n = r >> 7; int k = r & 127;
    W1t[i] = f2bf(sW1[((size_t)l * 128 + k) * 64 + n]);
  }
  if (i < 2 * 64 * 64) {
    int l = i >> 12; int r = i & 4095; int n = r >> 6; int k = r & 63;
    W2t[i] = f2bf(sW2[((size_t)l * 64 + k) * 64 + n]);
  }
  if (i < 64 * 64) {
    int c = i >> 6, k = i & 63;
    cW1t[i] = f2bf(cW1[k * 64 + c]);
  }
  if (i < 32 * 64) {
    int c = i >> 6, k = i & 63;
    cW2t[i] = f2bf(cW2[k * 32 + c]);
  }
}

// ---------------------------------------------------------------------------
// Phase 1 edge kernel (MFMA, barrier-free wave-private 16-edge tiles).
// bounds(256,3), grid 768 — R13 config. DO NOT change bounds or grid:
// R6/R7/R14 (tighter bounds) -> weight remat (FETCH 10x); R15 (grid 1280) ->
// occupancy unchanged, dur +15%. Sharp local optimum.
// ---------------------------------------------------------------------------
__global__ __launch_bounds__(256, 3) void phase1_edge_mfma(
    const unsigned short* __restrict__ xb, const int* __restrict__ dstS,
    const int2* __restrict__ srcdtS, const float* __restrict__ freq,
    const float* __restrict__ phs,
    const unsigned short* __restrict__ W1t1, const float* __restrict__ b1,
    const unsigned short* __restrict__ W2t1, const float* __restrict__ b2,
    float* __restrict__ accum, int E, int nwt)
{
  __shared__ unsigned short sA[64][104];
  __shared__ unsigned short sHid[64][72];
  __shared__ float sRed[64][20];
  __shared__ int   sDst[64];

  const int t = threadIdx.x;
  const int wv = t >> 6, lane = t & 63, l16 = lane & 15, quad = lane >> 4;
  const int r0 = wv * 16;

  s16x8 w1f[3][3], w2f[2][2];
  float bias1[3], bias2[2];
#pragma unroll
  for (int cb = 0; cb < 3; cb++) {
    int n = cb * 16 + l16;
#pragma unroll
    for (int kb = 0; kb < 3; kb++)
      w1f[cb][kb] = *(const s16x8*)&W1t1[n * 96 + kb * 32 + quad * 8];
    bias1[cb] = (n < 33) ? b1[n] : 0.0f;
  }
#pragma unroll
  for (int cb = 0; cb < 2; cb++) {
    int n = cb * 16 + l16;
#pragma unroll
    for (int kb = 0; kb < 2; kb++)
      w2f[cb][kb] = *(const s16x8*)&W2t1[n * 64 + kb * 32 + quad * 8];
    bias2[cb] = (n < 17) ? b2[n] : 0.0f;
  }

  // zero own-wave pad columns once
  for (int i = lane; i < 16 * 28; i += 64) {
    int rr = r0 + i / 28, c = i % 28;
    int col = (c < 6) ? 18 + c : (c < 12) ? 42 + (c - 6) : 80 + (c - 12);
    sA[rr][col] = 0;
  }
  for (int i = lane; i < 256; i += 64)
    sHid[r0 + (i >> 4)][48 + (i & 15)] = 0;

  const int gw = blockIdx.x * 4 + wv;
  const int nw = gridDim.x * 4;

  for (int tile = gw; tile < nwt; tile += nw) {
    const int eb = tile << 4;

    // staging: 4 lanes/edge (q0 xi, q1 xj, q2/q3 rel halves) — own rows only
    {
      int e_loc = lane >> 2, q = lane & 3;
      int rr = r0 + e_loc;
      int er = eb + e_loc; if (er >= E) er = E - 1;
      if (q < 2) {
        int node = q ? srcdtS[er].x : dstS[er];
        if (!q) sDst[rr] = node;
        const unsigned short* src = &xb[(size_t)node * 24];
        int base = q ? 24 : 0;
        *(uint4*)&sA[rr][base]     = *(const uint4*)&src[0];
        *(uint4*)&sA[rr][base + 8] = *(const uint4*)&src[8];
        *(unsigned int*)&sA[rr][base + 16] = *(const unsigned int*)&src[16];
      } else {
        float dt = __int_as_float(srcdtS[er].y);
        int k0 = (q == 2) ? 0 : 16;
        unsigned short tmp[16] __attribute__((aligned(16)));
#pragma unroll
        for (int j = 0; j < 16; j++)
          tmp[j] = f2bf(__cosf(fmaf(dt, freq[k0 + j], phs[k0 + j])));
        *(uint4*)&sA[rr][48 + k0]     = *(const uint4*)&tmp[0];
        *(uint4*)&sA[rr][48 + k0 + 8] = *(const uint4*)&tmp[8];
      }
    }

    // pass1: hid = relu(A @ W1 + b1)   (own row r0+l16)
    f32x4 a1[3];
#pragma unroll
    for (int cb = 0; cb < 3; cb++)
      a1[cb] = (f32x4){bias1[cb], bias1[cb], bias1[cb], bias1[cb]};
#pragma unroll
    for (int kb = 0; kb < 3; kb++) {
      s16x8 aF = *(const s16x8*)&sA[r0 + l16][kb * 32 + quad * 8];
#pragma unroll
      for (int cb = 0; cb < 3; cb++)
        a1[cb] = __builtin_amdgcn_mfma_f32_16x16x32_bf16(aF, w1f[cb][kb], a1[cb], 0, 0, 0);
    }
#pragma unroll
    for (int cb = 0; cb < 3; cb++)
#pragma unroll
      for (int reg = 0; reg < 4; reg++)
        sHid[r0 + quad * 4 + reg][cb * 16 + l16] = f2bf(fmaxf(a1[cb][reg], 0.0f));

    // pass2: u = hid @ W2 + b2
    f32x4 a2[2];
#pragma unroll
    for (int cb = 0; cb < 2; cb++)
      a2[cb] = (f32x4){bias2[cb], bias2[cb], bias2[cb], bias2[cb]};
#pragma unroll
    for (int kb = 0; kb < 2; kb++) {
      s16x8 aF = *(const s16x8*)&sHid[r0 + l16][kb * 32 + quad * 8];
#pragma unroll
      for (int cb = 0; cb < 2; cb++)
        a2[cb] = __builtin_amdgcn_mfma_f32_16x16x32_bf16(aF, w2f[cb][kb], a2[cb], 0, 0, 0);
    }

    // f -> sRed (own rows)
#pragma unroll
    for (int reg = 0; reg < 4; reg++) {
      int row = r0 + quad * 4 + reg;
      bool ok = (eb + quad * 4 + reg < E);
      sRed[row][l16] = ok ? tanh_factor(a2[0][reg]) : 0.0f;
      if (l16 == 0) sRed[row][16] = ok ? tanh_factor(a2[1][reg]) : 0.0f;
    }

    // wave-local segmented walk: lanes 0..16, col = lane, own 16 rows
    if (lane < 17) {
      int col = lane;
      float run = 0.0f;
      int cur = sDst[r0];
#pragma unroll
      for (int k = 0; k < 16; k++) {
        int d = sDst[r0 + k];
        float v = sRed[r0 + k][col];
        if (d != cur) {
          atomic_add_f32(&accum[(size_t)cur * 17 + col], run);
          run = 0.0f; cur = d;
        }
        run += v;
      }
      atomic_add_f32(&accum[(size_t)cur * 17 + col], run);
    }
  }
}

// ---------------------------------------------------------------------------
// Phase 1 node kernel: h[n] = (x[n] * (1 + acc/max(cnt,1))) @ projW + projb.
// Also zeroes acc2 (replaces a 25.6MB memset dispatch).
// ---------------------------------------------------------------------------
__global__ __launch_bounds__(256) void phase1_node(
    const float* __restrict__ x, const float* __restrict__ acc1,
    const int* __restrict__ cntI, const float* __restrict__ Wp,
    const float* __restrict__ bp, float* __restrict__ h,
    float* __restrict__ acc2, int N)
{
  __shared__ float s0[4][20];
  const int t = threadIdx.x;
  const int nb = blockIdx.x << 2;
  if (t < 68) {
    int nl = t / 17, c = t % 17;
    int n = nb + nl;
    float v = 0.0f;
    if (n < N) {
      float cnt = fmaxf((float)cntI[n], 1.0f);
      v = x[n * 17 + c] * (1.0f + acc1[n * 17 + c] / cnt);
    }
    s0[nl][c] = v;
  }
  __syncthreads();
  int nl = t >> 6, j = t & 63;
  int n = nb + nl;
  if (n < N) {
    float acc = bp[j];
#pragma unroll
    for (int c = 0; c < 17; c++) acc = fmaf(s0[nl][c], Wp[c * 64 + j], acc);
    h[n * 64 + j] = acc;
    acc2[n * 64 + j] = 0.0f;
  }
}

// ---------------------------------------------------------------------------
// prep_P<DO_BN>: P1[n] = h'[n]@W1a + b1, P2[n] = h'[n]@W1b where
// h' = DO_BN ? relu(BN(h)) : h. DO_BN also writes h' back (guarded vs the
// row-clamp race: only the owning block writes).
// ---------------------------------------------------------------------------
template <bool DO_BN>
__global__ void prep_P(
    float* __restrict__ h, const unsigned short* __restrict__ W1t,
    const float* __restrict__ b1,
    const float* __restrict__ bns, const float* __restrict__ bnq,
    const float* __restrict__ gam, const float* __restrict__ bet, float invR,
    unsigned short* __restrict__ P1, unsigned short* __restrict__ P2, int N)
{
  __shared__ unsigned short sH[64][72];
  __shared__ float sM[64], sS[64], sB[64];
  const int t = threadIdx.x;
  const int wv = t >> 6, lane = t & 63, l16 = lane & 15, quad = lane >> 4;
  const int nb = blockIdx.x << 6;

  if (DO_BN) {
    if (t < 64) {
      float m = bns[t] * invR;
      float var = bnq[t] * invR - m * m;
      sM[t] = m;
      sS[t] = gam[t] * rsqrtf(var + 1e-5f);
      sB[t] = bet[t];
    }
    __syncthreads();
  }

#pragma unroll
  for (int i = 0; i < 4; i++) {
    int g = t + i * 256;
    int r = g >> 4, c4 = (g & 15) << 2;
    int n0 = nb + r;
    bool valid = (n0 < N);
    int n = valid ? n0 : N - 1;
    float4 v = *(const float4*)&h[(size_t)n * 64 + c4];
    if (DO_BN) {
      v.x = fmaxf(fmaf(v.x - sM[c4 + 0], sS[c4 + 0], sB[c4 + 0]), 0.0f);
      v.y = fmaxf(fmaf(v.y - sM[c4 + 1], sS[c4 + 1], sB[c4 + 1]), 0.0f);
      v.z = fmaxf(fmaf(v.z - sM[c4 + 2], sS[c4 + 2], sB[c4 + 2]), 0.0f);
      v.w = fmaxf(fmaf(v.w - sM[c4 + 3], sS[c4 + 3], sB[c4 + 3]), 0.0f);
      if (valid) *(float4*)&h[(size_t)n0 * 64 + c4] = v;
    }
    ushort4 o = { f2bf(v.x), f2bf(v.y), f2bf(v.z), f2bf(v.w) };
    *(ushort4*)&sH[r][c4] = o;
  }
  __syncthreads();

  const int n = nb + wv * 16 + l16;
#pragma unroll
  for (int half = 0; half < 2; half++) {
    f32x4 acc[4];
#pragma unroll
    for (int cb = 0; cb < 4; cb++) {
      if (half == 0) {
        float4 bv = *(const float4*)&b1[cb * 16 + quad * 4];
        acc[cb] = (f32x4){bv.x, bv.y, bv.z, bv.w};
      } else {
        acc[cb] = (f32x4){0.0f, 0.0f, 0.0f, 0.0f};
      }
    }
#pragma unroll
    for (int kb = 0; kb < 2; kb++) {
      s16x8 bF = *(const s16x8*)&sH[wv * 16 + l16][kb * 32 + quad * 8];
#pragma unroll
      for (int cb = 0; cb < 4; cb++) {
        s16x8 aF = *(const s16x8*)&W1t[(cb * 16 + l16) * 128 + half * 64 + kb * 32 + quad * 8];
        acc[cb] = __builtin_amdgcn_mfma_f32_16x16x32_bf16(aF, bF, acc[cb], 0, 0, 0);
      }
    }
    if (n < N) {
      unsigned short* P = half ? P2 : P1;
#pragma unroll
      for (int cb = 0; cb < 4; cb++) {
        ushort4 o = { f2bf(acc[cb][0]), f2bf(acc[cb][1]),
                      f2bf(acc[cb][2]), f2bf(acc[cb][3]) };
        *(ushort4*)&P[(size_t)n * 64 + cb * 16 + quad * 4] = o;
      }
    }
  }
}

// ---------------------------------------------------------------------------
// Phase 2 edge kernel — barrier-free wave-private 16-edge tiles.
// bounds(256,4), grid 1024 — R13 config (see phase1 note).
// ---------------------------------------------------------------------------
__global__ __launch_bounds__(256, 4) void phase2_edge(
    const unsigned short* __restrict__ P1, const unsigned short* __restrict__ P2,
    const int* __restrict__ dstS, const int2* __restrict__ srcdtS,
    const unsigned short* __restrict__ W2t, const float* __restrict__ b2,
    float* __restrict__ accum, int E, int nwt)
{
  __shared__ unsigned short sA[64][136];   // [edge][0:64]=P1[dst], [64:128]=P2[src]
  __shared__ int sDst[64];
  float* sRedF = (float*)&sA[0][0];        // aliased 64x68 f32 (same stride 272B)

  const int t = threadIdx.x;
  const int wv = t >> 6, lane = t & 63, l16 = lane & 15, quad = lane >> 4;
  const int r0 = wv * 16;

  s16x8 w2f[4][2];
  f32x4 bias2v[4];
#pragma unroll
  for (int cb = 0; cb < 4; cb++) {
#pragma unroll
    for (int kb = 0; kb < 2; kb++)
      w2f[cb][kb] = *(const s16x8*)&W2t[(cb * 16 + l16) * 64 + kb * 32 + quad * 8];
    float4 bv = *(const float4*)&b2[cb * 16 + quad * 4];
    bias2v[cb] = (f32x4){bv.x, bv.y, bv.z, bv.w};
  }

  const int gw = blockIdx.x * 4 + wv;
  const int nw = gridDim.x * 4;
  const int eRow = r0 + l16;

  for (int tile = gw; tile < nwt; tile += nw) {
    const int eb = tile << 4;

    // staging: 4 lanes/edge, 64B contiguous per lane, own rows only
    {
      int e_loc = lane >> 2, q = lane & 3;
      int rr = r0 + e_loc;
      int er = eb + e_loc; if (er >= E) er = E - 1;
      int node;
      if (q < 2) { node = dstS[er]; if (!q) sDst[rr] = node; }
      else       node = srcdtS[er].x;
      const unsigned short* src = (q < 2 ? P1 : P2) + (size_t)node * 64 + (q & 1) * 32;
      int cb0 = q * 32;
#pragma unroll
      for (int j = 0; j < 4; j++)
        *(uint4*)&sA[rr][cb0 + j * 8] = *(const uint4*)&src[j * 8];
    }

    // hidden B-frags: relu(P1+P2), packed bf16 (own row)
    s16x8 hidf[2];
#pragma unroll
    for (int kb = 0; kb < 2; kb++) {
      s16x8 x1 = *(const s16x8*)&sA[eRow][kb * 32 + quad * 8];
      s16x8 x2 = *(const s16x8*)&sA[eRow][64 + kb * 32 + quad * 8];
      s16x8 hf;
#pragma unroll
      for (int j = 0; j < 8; j++) {
        float a = bf2f((unsigned short)x1[j]);
        float b = bf2f((unsigned short)x2[j]);
        hf[j] = (short)f2bf(fmaxf(a + b, 0.0f));
      }
      hidf[kb] = hf;
    }

    // u^T[n2][edge] = W2t @ hidden^T + b2
    f32x4 acc[4];
#pragma unroll
    for (int cb = 0; cb < 4; cb++) acc[cb] = bias2v[cb];
#pragma unroll
    for (int kb = 0; kb < 2; kb++)
#pragma unroll
      for (int cb = 0; cb < 4; cb++)
        acc[cb] = __builtin_amdgcn_mfma_f32_16x16x32_bf16(w2f[cb][kb], hidf[kb], acc[cb], 0, 0, 0);

    // f = 2*tanh(u)-1 -> sRedF (own rows; same-wave ordering)
    bool ok = (eb + l16 < E);
#pragma unroll
    for (int cb = 0; cb < 4; cb++) {
      f32x4 f;
#pragma unroll
      for (int reg = 0; reg < 4; reg++)
        f[reg] = ok ? tanh_factor(acc[cb][reg]) : 0.0f;
      *(f32x4*)&sRedF[eRow * 68 + cb * 16 + quad * 4] = f;
    }

    // wave-local segmented walk: lane = col, own 16 rows
    {
      float run = 0.0f;
      int cur = sDst[r0];
#pragma unroll
      for (int k = 0; k < 16; k++) {
        int d = sDst[r0 + k];                 // wave-uniform
        float v = sRedF[(r0 + k) * 68 + lane];
        if (d != cur) {                       // wave-uniform branch
          atomic_add_f32(&accum[(size_t)cur * 64 + lane], run);
          run = 0.0f; cur = d;
        }
        run += v;
      }
      atomic_add_f32(&accum[(size_t)cur * 64 + lane], run);
    }
  }
}

// ---------------------------------------------------------------------------
// Node update + BN statistics; re-zeroes accum for the next layer.
// ---------------------------------------------------------------------------
__global__ __launch_bounds__(256) void node_update_bn(
    float* __restrict__ h, float* __restrict__ accum,
    const int* __restrict__ cntI, float* __restrict__ bns,
    float* __restrict__ bnq, int N)
{
  const int t = threadIdx.x;
  float ls = 0.0f, lq = 0.0f;
  int total = N * 64;
  for (int idx = blockIdx.x * 256 + t; idx < total; idx += gridDim.x * 256) {
    int n = idx >> 6;
    float cnt = fmaxf((float)cntI[n], 1.0f);
    float v = h[idx] * (1.0f + accum[idx] / cnt);
    accum[idx] = 0.0f;                 // ready for next layer's scatter
    h[idx] = v;
    ls += v; lq += v * v;
  }
  __shared__ float ss[256], sq[256];
  ss[t] = ls; sq[t] = lq;
  __syncthreads();
  if (t < 64) {
    float s = ss[t] + ss[t + 64] + ss[t + 128] + ss[t + 192];
    float q = sq[t] + sq[t + 64] + sq[t + 128] + sq[t + 192];
    atomic_add_f32(&bns[t], s);
    atomic_add_f32(&bnq[t], q);
  }
}

// ---------------------------------------------------------------------------
// Classifier MFMA with input-BN fused at staging:
//   in' = relu(BN(in)) via (ibns,ibnq,igam,ibet,iinvR); z = in' @ Wt^T + bias;
//   accumulates output BN stats (bns,bnq) for the next stage.
// ---------------------------------------------------------------------------
template <int NCB>
__global__ __launch_bounds__(256) void clf_mfma(
    const float* __restrict__ in, const unsigned short* __restrict__ Wt,
    const float* __restrict__ bias, float* __restrict__ z,
    float* __restrict__ bns, float* __restrict__ bnq,
    const float* __restrict__ ibns, const float* __restrict__ ibnq,
    const float* __restrict__ igam, const float* __restrict__ ibet,
    float iinvR, int rows)
{
  __shared__ unsigned short sIn[64][72];
  __shared__ float sM[64], sS[64], sB[64];
  const int t = threadIdx.x;
  const int wv = t >> 6, lane = t & 63, l16 = lane & 15, quad = lane >> 4;
  const int nb = blockIdx.x << 6;

  if (t < 64) {
    float m = ibns[t] * iinvR;
    float var = ibnq[t] * iinvR - m * m;
    sM[t] = m;
    sS[t] = igam[t] * rsqrtf(var + 1e-5f);
    sB[t] = ibet[t];
  }

  s16x8 wf[NCB][2];
  f32x4 bv[NCB];
#pragma unroll
  for (int cb = 0; cb < NCB; cb++) {
#pragma unroll
    for (int kb = 0; kb < 2; kb++)
      wf[cb][kb] = *(const s16x8*)&Wt[(cb * 16 + l16) * 64 + kb * 32 + quad * 8];
    float4 b4 = *(const float4*)&bias[cb * 16 + quad * 4];
    bv[cb] = (f32x4){b4.x, b4.y, b4.z, b4.w};
  }
  __syncthreads();   // sM/sS/sB visible

#pragma unroll
  for (int i = 0; i < 4; i++) {
    int g = t + i * 256;
    int r = g >> 4, c4 = (g & 15) << 2;
    int n = nb + r; if (n >= rows) n = rows - 1;
    float4 v = *(const float4*)&in[(size_t)n * 64 + c4];
    v.x = fmaxf(fmaf(v.x - sM[c4 + 0], sS[c4 + 0], sB[c4 + 0]), 0.0f);
    v.y = fmaxf(fmaf(v.y - sM[c4 + 1], sS[c4 + 1], sB[c4 + 1]), 0.0f);
    v.z = fmaxf(fmaf(v.z - sM[c4 + 2], sS[c4 + 2], sB[c4 + 2]), 0.0f);
    v.w = fmaxf(fmaf(v.w - sM[c4 + 3], sS[c4 + 3], sB[c4 + 3]), 0.0f);
    ushort4 o = { f2bf(v.x), f2bf(v.y), f2bf(v.z), f2bf(v.w) };
    *(ushort4*)&sIn[r][c4] = o;
  }
  __syncthreads();

  const int n = nb + wv * 16 + l16;
  const bool ok = (n < rows);
  f32x4 acc[NCB];
#pragma unroll
  for (int cb = 0; cb < NCB; cb++) acc[cb] = bv[cb];
#pragma unroll
  for (int kb = 0; kb < 2; kb++) {
    s16x8 bF = *(const s16x8*)&sIn[wv * 16 + l16][kb * 32 + quad * 8];
#pragma unroll
    for (int cb = 0; cb < NCB; cb++)
      acc[cb] = __builtin_amdgcn_mfma_f32_16x16x32_bf16(wf[cb][kb], bF, acc[cb], 0, 0, 0);
  }

  // store z (f32) + per-col stats reduced over the wave's 16 rows
#pragma unroll
  for (int cb = 0; cb < NCB; cb++) {
    if (ok)
      *(float4*)&z[(size_t)n * (NCB * 16) + cb * 16 + quad * 4] =
          make_float4(acc[cb][0], acc[cb][1], acc[cb][2], acc[cb][3]);
    f32x4 s, q;
#pragma unroll
    for (int reg = 0; reg < 4; reg++) {
      float v = ok ? acc[cb][reg] : 0.0f;
      s[reg] = v; q[reg] = v * v;
    }
#pragma unroll
    for (int m = 1; m < 16; m <<= 1) {
#pragma unroll
      for (int reg = 0; reg < 4; reg++) {
        s[reg] += __shfl_xor(s[reg], m);
        q[reg] += __shfl_xor(q[reg], m);
      }
    }
    if (l16 == 0) {
#pragma unroll
      for (int reg = 0; reg < 4; reg++) {
        int col = cb * 16 + quad * 4 + reg;
        atomic_add_f32(&bns[col], s[reg]);
        atomic_add_f32(&bnq[col], q[reg]);
      }
    }
  }
}

// clf_final with fused input BN (slot stats over 32 cols).
__global__ __launch_bounds__(256) void clf_final(
    const float* __restrict__ z2, const float* __restrict__ W3,
    const float* __restrict__ b3,
    const float* __restrict__ ibns, const float* __restrict__ ibnq,
    const float* __restrict__ igam, const float* __restrict__ ibet,
    float iinvR, float* __restrict__ out, int rows)
{
  __shared__ float sM[32], sS[32], sB[32];
  const int t = threadIdx.x;
  if (t < 32) {
    float m = ibns[t] * iinvR;
    float var = ibnq[t] * iinvR - m * m;
    sM[t] = m;
    sS[t] = igam[t] * rsqrtf(var + 1e-5f);
    sB[t] = ibet[t];
  }
  __syncthreads();
  int n = blockIdx.x * 256 + t;
  if (n >= rows) return;
  float acc = b3[0];
#pragma unroll
  for (int k = 0; k < 32; k++) {
    float v = fmaxf(fmaf(z2[n * 32 + k] - sM[k], sS[k], sB[k]), 0.0f);
    acc = fmaf(v, W3[k], acc);
  }
  out[n] = acc;
}

// ---------------------------------------------------------------------------
extern "C" void kernel_launch(void* const* d_in, const int* in_sizes, int n_in,
                              void* d_out, int out_size, void* d_ws, size_t ws_size,
                              hipStream_t stream)
{
  const float* x    = (const float*)d_in[0];
  const int*   ei   = (const int*)  d_in[1];
  const float* dts  = (const float*)d_in[2];
  const float* freq = (const float*)d_in[4];
  const float* phs  = (const float*)d_in[5];
  const float* tW1  = (const float*)d_in[6];
  const float* tb1  = (const float*)d_in[7];
  const float* tW2  = (const float*)d_in[8];
  const float* tb2  = (const float*)d_in[9];
  const float* pW   = (const float*)d_in[10];
  const float* pb   = (const float*)d_in[11];
  const float* sW1  = (const float*)d_in[12];
  const float* sb1  = (const float*)d_in[13];
  const float* sW2  = (const float*)d_in[14];
  const float* sb2  = (const float*)d_in[15];
  const float* bng  = (const float*)d_in[16];
  const float* bnb  = (const float*)d_in[17];
  const float* cW1  = (const float*)d_in[18];
  const float* cb1  = (const float*)d_in[19];
  const float* cg1  = (const float*)d_in[20];
  const float* cbb1 = (const float*)d_in[21];
  const float* cW2  = (const float*)d_in[22];
  const float* cb2  = (const float*)d_in[23];
  const float* cg2  = (const float*)d_in[24];
  const float* cbb2 = (const float*)d_in[25];
  const float* cW3  = (const float*)d_in[26];
  const float* cb3  = (const float*)d_in[27];
  float* out = (float*)d_out;

  const int N = in_sizes[0] / 17;
  const int E = in_sizes[1] / 2;
  const int B = out_size;

  // ---- workspace layout (byte offsets, union region for phase-local data) --
  char* base = (char*)d_ws;
  size_t off = 0;
  float* h    = (float*)(base + off); off += (size_t)N * 64 * 4;
  float* acc2 = (float*)(base + off); off += (size_t)N * 64 * 4;
  char*  uni  = base + off;           off += (size_t)N * 64 * 4;  // union
  float* bnsAll = (float*)(base + off); off += 8 * 64 * 4;        // 4 slot pairs
  unsigned short* W1t = (unsigned short*)(base + off); off += 2 * 64 * 128 * 2;
  unsigned short* W2t = (unsigned short*)(base + off); off += 2 * 64 * 64 * 2;
  unsigned short* cW1t = (unsigned short*)(base + off); off += 64 * 64 * 2;
  unsigned short* cW2t = (unsigned short*)(base + off); off += 32 * 64 * 2;
  int* cntI   = (int*)(base + off); off += (size_t)N * 4;
  int* cursor = (int*)(base + off); off += (size_t)N * 4;
  int* bsum   = (int*)(base + off); off += 512 * 4;
  int* dstS   = (int*)(base + off); off += (size_t)E * 4;
  off = (off + 15) & ~(size_t)15;
  int2* srcdtS = (int2*)(base + off); off += (size_t)E * 8;
  size_t needed = off;
  if (ws_size < needed) return;  // fail visibly (output stays poisoned)

  // union members (phase1 | phase2 | classifier — lifetimes disjoint)
  float* acc1 = (float*)uni;                                     // N*17 f32
  unsigned short* xb   = (unsigned short*)(uni + (size_t)N * 17 * 4); // N*24
  unsigned short* W1t1 = xb + (size_t)N * 24;                    // 48*96
  unsigned short* W2t1 = W1t1 + 48 * 96;                         // 32*64
  unsigned short* P1 = (unsigned short*)uni;                     // N*64
  unsigned short* P2 = P1 + (size_t)N * 64;                      // N*64
  float* z1 = (float*)uni;                                       // B*64
  float* z2 = z1 + (size_t)B * 64;                               // B*32

  const int nwt = (E + 15) / 16;
  const int NB = (N + 255) / 256;
  if (NB > 512) return;

  // ---- init (poisoned ws): counts, acc1, BN-stat slots ----
  hipMemsetAsync(cntI, 0, (size_t)N * 4, stream);
  hipMemsetAsync(acc1, 0, (size_t)N * 17 * 4, stream);
  hipMemsetAsync(bnsAll, 0, 8 * 64 * 4, stream);

  // ---- counting sort by dst (yields counts + dstS) + weight/x prep ----
  k_hist<<<(E + 255) / 256, 256, 0, stream>>>(ei, cntI, E);
  k_scan_block<<<NB, 256, 0, stream>>>(cntI, cursor, bsum, N);
  k_scan_bsum<<<1, 512, 0, stream>>>(bsum, NB);
  k_expand_add<<<NB, 256, 0, stream>>>(cursor, bsum, cntI, dstS, N);
  k_scatter_x<<<1024, 256, 0, stream>>>(ei, dts, cursor, srcdtS, E, N);
  prep_all<<<(N * 24 + 255) / 256, 256, 0, stream>>>(
      x, tW1, tW2, sW1, sW2, cW1, cW2, xb, W1t1, W2t1, W1t, W2t, cW1t, cW2t, N);

  // ---- phase 1 (R13 grids) ----
  phase1_edge_mfma<<<768, 256, 0, stream>>>(
      xb, dstS, srcdtS, freq, phs, W1t1, tb1, W2t1, tb2, acc1, E, nwt);
  phase1_node<<<(N + 3) / 4, 256, 0, stream>>>(x, acc1, cntI, pW, pb, h, acc2, N);

  // ---- phase 2: L = 2 layers; BN(l) fused into the next consumer ----
  const int PB = (N + 63) / 64;
  // l = 0
  prep_P<false><<<PB, 256, 0, stream>>>(
      h, W1t, sb1, nullptr, nullptr, nullptr, nullptr, 0.0f, P1, P2, N);
  phase2_edge<<<1024, 256, 0, stream>>>(
      P1, P2, dstS, srcdtS, W2t, sb2, acc2, E, nwt);
  node_update_bn<<<1024, 256, 0, stream>>>(h, acc2, cntI,
                                           bnsAll + 0, bnsAll + 64, N);
  // l = 1 (prep_P applies BN of layer 0 and writes post-BN h back)
  prep_P<true><<<PB, 256, 0, stream>>>(
      h, W1t + (size_t)64 * 128, sb1 + 64, bnsAll + 0, bnsAll + 64,
      bng, bnb, 1.0f / (float)N, P1, P2, N);
  phase2_edge<<<1024, 256, 0, stream>>>(
      P1, P2, dstS, srcdtS, W2t + (size_t)64 * 64, sb2 + 64, acc2, E, nwt);
  node_update_bn<<<1024, 256, 0, stream>>>(h, acc2, cntI,
                                           bnsAll + 128, bnsAll + 192, N);

  // ---- classifier: BN of layer 1 fused into clf_mfma<4> staging ----
  const int CB = (B + 63) / 64;
  clf_mfma<4><<<CB, 256, 0, stream>>>(
      h, cW1t, cb1, z1, bnsAll + 256, bnsAll + 320,
      bnsAll + 128, bnsAll + 192, bng + 64, bnb + 64, 1.0f / (float)N, B);
  clf_mfma<2><<<CB, 256, 0, stream>>>(
      z1, cW2t, cb2, z2, bnsAll + 384, bnsAll + 448,
      bnsAll + 256, bnsAll + 320, cg1, cbb1, 1.0f / (float)B, B);
  clf_final<<<(B + 255) / 256, 256, 0, stream>>>(
      z2, cW3, cb3, bnsAll + 384, bnsAll + 448, cg2, cbb2,
      1.0f / (float)B, out, B);
}